// Round 11
// baseline (332.033 us; speedup 1.0000x reference)
//
#include <hip/hip_runtime.h>
#include <math.h>

// GAT 2-layer: N=10000, E=160000 (+N self loops), IN=128, H1=8, C1=128, OUT=64.
// R11: edge-parallel softmax-weight precompute (w1k/w2k, no max subtraction --
//      logits are O(1) with glorot weights) + pure-gather aggregation kernels
//      (x row read once per wave, no shuffles/exp in the gather loop).
//      GEMMs stay bf16 MFMA from R8.

#define NEG_SLOPE 0.2f

typedef short bf16x8 __attribute__((ext_vector_type(8)));
typedef float f32x4 __attribute__((ext_vector_type(4)));

__device__ __forceinline__ float leaky(float v) { return v >= 0.0f ? v : NEG_SLOPE * v; }

__device__ __forceinline__ unsigned short f2bf(float f) {
    unsigned u = __float_as_uint(f);
    u += 0x7FFFu + ((u >> 16) & 1u);   // round-to-nearest-even
    return (unsigned short)(u >> 16);
}

// ---------------- CSR build ----------------

__global__ void count_kernel(const int* __restrict__ ei, int* __restrict__ counts, int E, int N) {
    int i = blockIdx.x * blockDim.x + threadIdx.x;
    int M = E + N;
    if (i >= M) return;
    int dst = (i < E) ? ei[E + i] : (i - E);   // self-loop tail
    atomicAdd(&counts[dst], 1);
}

// single-block scan: serial per-thread sums + wave shuffle scan (2 barriers)
__global__ __launch_bounds__(1024) void scan_kernel(
    const int* __restrict__ counts, int* __restrict__ offsets,
    int* __restrict__ cursor, int N) {
    __shared__ int wsum[16];
    int t = threadIdx.x;
    int per = (N + 1023) / 1024;
    int base = t * per;
    int s = 0;
    for (int j = 0; j < per; j++) {
        int idx = base + j;
        if (idx < N) s += counts[idx];
    }
    int lane = t & 63, wid = t >> 6;
    int inc = s;
#pragma unroll
    for (int off = 1; off <= 32; off <<= 1) {
        int v = __shfl_up(inc, off);
        if (lane >= off) inc += v;
    }
    if (lane == 63) wsum[wid] = inc;
    __syncthreads();
    if (t < 16) {
        int v = wsum[t];
        int iv = v;
#pragma unroll
        for (int off = 1; off <= 8; off <<= 1) {
            int u = __shfl_up(iv, off);
            if (t >= off) iv += u;
        }
        wsum[t] = iv - v;   // exclusive
    }
    __syncthreads();
    int run = wsum[wid] + inc - s;
    for (int j = 0; j < per; j++) {
        int idx = base + j;
        if (idx < N) {
            offsets[idx] = run;
            cursor[idx] = run;
            run += counts[idx];
        }
    }
    if (t == 1023) offsets[N] = run;
}

__global__ void fill_kernel(const int* __restrict__ ei, int* __restrict__ cursor,
                            int* __restrict__ srcs, int* __restrict__ dsts, int E, int N) {
    int i = blockIdx.x * blockDim.x + threadIdx.x;
    int M = E + N;
    if (i >= M) return;
    int src, dst;
    if (i < E) { src = ei[i]; dst = ei[E + i]; }
    else       { src = dst = i - E; }
    int pos = atomicAdd(&cursor[dst], 1);
    srcs[pos] = src;
    dsts[pos] = dst;
}

// ---------------- prep_all: As/Ad + W1->W1bT [h][c][k] bf16 + W2->W2bT [c][k] bf16 ---

__global__ __launch_bounds__(256) void prep_all(
    const float* __restrict__ W1, const float* __restrict__ a_src1,
    const float* __restrict__ a_dst1, const float* __restrict__ W2,
    float* __restrict__ As, float* __restrict__ Ad,
    unsigned short* __restrict__ W1bT, unsigned short* __restrict__ W2bT) {
    int b = blockIdx.x;
    __shared__ unsigned short tile[32][33];
    if (b < 4) {
        int i = b * 256 + threadIdx.x;   // 0..1023
        int k = i >> 3, h = i & 7;
        float ss = 0.f, sd = 0.f;
        for (int c = 0; c < 128; c += 4) {
            float4 w = *(const float4*)(W1 + (size_t)k * 1024 + h * 128 + c);
            float4 a = *(const float4*)(a_src1 + h * 128 + c);
            float4 d = *(const float4*)(a_dst1 + h * 128 + c);
            ss += w.x * a.x + w.y * a.y + w.z * a.z + w.w * a.w;
            sd += w.x * d.x + w.y * d.y + w.z * d.z + w.w * d.w;
        }
        As[k * 8 + h] = ss;
        Ad[k * 8 + h] = sd;
    } else if (b < 132) {
        int bb = b - 4;
        int kt = bb & 3, hct = bb >> 2;
        int j = threadIdx.x & 31;
        int i0 = threadIdx.x >> 5;
        for (int i = i0; i < 32; i += 8)
            tile[i][j] = f2bf(W1[(size_t)(kt * 32 + i) * 1024 + hct * 32 + j]);
        __syncthreads();
        for (int i = i0; i < 32; i += 8) {
            int hc = hct * 32 + i, k = kt * 32 + j;
            int h = hc >> 7, c = hc & 127;
            W1bT[h * 16384 + c * 128 + k] = tile[j][i];
        }
    } else {
        int bb = b - 132;
        int kt = bb & 31, ctile = bb >> 5;
        int j = threadIdx.x & 31;
        int i0 = threadIdx.x >> 5;
        for (int i = i0; i < 32; i += 8)
            tile[i][j] = f2bf(W2[(size_t)(kt * 32 + i) * 64 + ctile * 32 + j]);
        __syncthreads();
        for (int i = i0; i < 32; i += 8)
            W2bT[(size_t)(ctile * 32 + i) * 1024 + kt * 32 + j] = tile[j][i];
    }
}

// ---------------- alpha1: as1/ad1 = x @ As / Ad  [N,8] ----------------

__global__ __launch_bounds__(256) void alpha1_kernel(
    const float* __restrict__ x, const float* __restrict__ As, const float* __restrict__ Ad,
    float* __restrict__ as1, float* __restrict__ ad1, int N) {
    __shared__ float sAs[1024], sAd[1024];
    int t = threadIdx.x;
    {
        int i = t * 4;
        *(float4*)(sAs + i) = *(const float4*)(As + i);
        *(float4*)(sAd + i) = *(const float4*)(Ad + i);
    }
    __syncthreads();
    int node = blockIdx.x * 32 + (t >> 3);
    int h = t & 7;
    if (node >= N) return;
    float accs = 0.f, accd = 0.f;
    for (int k = 0; k < 128; k += 4) {
        float4 xv = *(const float4*)(x + (size_t)node * 128 + k);
        accs += xv.x * sAs[k * 8 + h] + xv.y * sAs[(k + 1) * 8 + h]
              + xv.z * sAs[(k + 2) * 8 + h] + xv.w * sAs[(k + 3) * 8 + h];
        accd += xv.x * sAd[k * 8 + h] + xv.y * sAd[(k + 1) * 8 + h]
              + xv.z * sAd[(k + 2) * 8 + h] + xv.w * sAd[(k + 3) * 8 + h];
    }
    as1[node * 8 + h] = accs;
    ad1[node * 8 + h] = accd;
}

// ---------------- w1k: edge-parallel layer-1 softmax numerators ----------------
// Thread per CSR slot: w[h] = exp(leaky(as1[s,h]+ad1[d,h])); atomicAdd wsum1[d,h].
// No max subtraction: logits are O(1) (glorot weights, unit-normal x).

__global__ __launch_bounds__(256) void w1k(
    const int* __restrict__ srcs, const int* __restrict__ dsts,
    const float* __restrict__ as1, const float* __restrict__ ad1,
    float* __restrict__ wbuf, float* __restrict__ wsum1, int M) {
    int e = blockIdx.x * 256 + threadIdx.x;
    if (e >= M) return;
    int s = srcs[e], d = dsts[e];
    float4 a0 = *(const float4*)(as1 + (size_t)s * 8);
    float4 a1 = *(const float4*)(as1 + (size_t)s * 8 + 4);
    float4 b0 = *(const float4*)(ad1 + (size_t)d * 8);
    float4 b1 = *(const float4*)(ad1 + (size_t)d * 8 + 4);
    float w[8];
    w[0] = __expf(leaky(a0.x + b0.x));
    w[1] = __expf(leaky(a0.y + b0.y));
    w[2] = __expf(leaky(a0.z + b0.z));
    w[3] = __expf(leaky(a0.w + b0.w));
    w[4] = __expf(leaky(a1.x + b1.x));
    w[5] = __expf(leaky(a1.y + b1.y));
    w[6] = __expf(leaky(a1.z + b1.z));
    w[7] = __expf(leaky(a1.w + b1.w));
    *(float4*)(wbuf + (size_t)e * 8)     = make_float4(w[0], w[1], w[2], w[3]);
    *(float4*)(wbuf + (size_t)e * 8 + 4) = make_float4(w[4], w[5], w[6], w[7]);
#pragma unroll
    for (int h = 0; h < 8; h++) atomicAdd(&wsum1[(size_t)d * 8 + h], w[h]);
}

// ---------------- l1_gather: wave per node, pure gather --------------------------
// Lane owns channels {lane*2, lane*2+1} of ALL 8 heads: x row loaded once/wave.

__global__ __launch_bounds__(256) void l1_gather(
    const float* __restrict__ x, const float* __restrict__ wbuf,
    const float* __restrict__ wsum1, const int* __restrict__ offsets,
    const int* __restrict__ srcs, unsigned short* __restrict__ y_b, int N) {
    int n = blockIdx.x * 4 + (threadIdx.x >> 6);
    if (n >= N) return;
    int lane = threadIdx.x & 63;
    int beg = offsets[n];
    int deg = offsets[n + 1] - beg;
    float2 acc[8];
#pragma unroll
    for (int h = 0; h < 8; h++) acc[h] = make_float2(0.f, 0.f);
    const float* xb = x + lane * 2;
#define L1G_BODY(I)                                                              \
    {                                                                            \
        int s_ = srcs[beg + (I)];                                                \
        float4 w0_ = *(const float4*)(wbuf + (size_t)(beg + (I)) * 8);           \
        float4 w1_ = *(const float4*)(wbuf + (size_t)(beg + (I)) * 8 + 4);       \
        float2 xv_ = *(const float2*)(xb + (size_t)s_ * 128);                    \
        acc[0].x = fmaf(w0_.x, xv_.x, acc[0].x); acc[0].y = fmaf(w0_.x, xv_.y, acc[0].y); \
        acc[1].x = fmaf(w0_.y, xv_.x, acc[1].x); acc[1].y = fmaf(w0_.y, xv_.y, acc[1].y); \
        acc[2].x = fmaf(w0_.z, xv_.x, acc[2].x); acc[2].y = fmaf(w0_.z, xv_.y, acc[2].y); \
        acc[3].x = fmaf(w0_.w, xv_.x, acc[3].x); acc[3].y = fmaf(w0_.w, xv_.y, acc[3].y); \
        acc[4].x = fmaf(w1_.x, xv_.x, acc[4].x); acc[4].y = fmaf(w1_.x, xv_.y, acc[4].y); \
        acc[5].x = fmaf(w1_.y, xv_.x, acc[5].x); acc[5].y = fmaf(w1_.y, xv_.y, acc[5].y); \
        acc[6].x = fmaf(w1_.z, xv_.x, acc[6].x); acc[6].y = fmaf(w1_.z, xv_.y, acc[6].y); \
        acc[7].x = fmaf(w1_.w, xv_.x, acc[7].x); acc[7].y = fmaf(w1_.w, xv_.y, acc[7].y); \
    }
    int i = 0;
    for (; i + 4 <= deg; i += 4) {       // 4 edges in flight
        L1G_BODY(i) L1G_BODY(i + 1) L1G_BODY(i + 2) L1G_BODY(i + 3)
    }
    for (; i < deg; i++) { L1G_BODY(i) }
#undef L1G_BODY
    float4 s0 = *(const float4*)(wsum1 + (size_t)n * 8);
    float4 s1 = *(const float4*)(wsum1 + (size_t)n * 8 + 4);
    float inv[8] = {1.f / (s0.x + 1e-16f), 1.f / (s0.y + 1e-16f),
                    1.f / (s0.z + 1e-16f), 1.f / (s0.w + 1e-16f),
                    1.f / (s1.x + 1e-16f), 1.f / (s1.y + 1e-16f),
                    1.f / (s1.z + 1e-16f), 1.f / (s1.w + 1e-16f)};
    unsigned short* dst = y_b + (size_t)n * 1024 + lane * 2;
#pragma unroll
    for (int h = 0; h < 8; h++) {
        unsigned lo = f2bf(acc[h].x * inv[h]);
        unsigned hi = f2bf(acc[h].y * inv[h]);
        *(unsigned*)(dst + h * 128) = lo | (hi << 16);   // coalesced per head
    }
}

// ---------------- l1_gemm (MFMA): hbuf_b = ELU(per-head y @ W1h + b1), bf16 out ----

__global__ __launch_bounds__(256) void l1_gemm(
    const unsigned short* __restrict__ y_b, const unsigned short* __restrict__ W1bT,
    const float* __restrict__ b1, unsigned short* __restrict__ hbuf_b, int N) {
    int h  = blockIdx.x & 7;
    int nb = (blockIdx.x >> 3) * 64;
    int w  = threadIdx.x >> 6;
    int lane = threadIdx.x & 63;
    int n16 = lane & 15, quad = lane >> 4;
    int node_a = nb + w * 16 + n16;
    const unsigned short* yrow =
        y_b + (size_t)(node_a < N ? node_a : 0) * 1024 + h * 128 + quad * 8;
    const unsigned short* Wh = W1bT + h * 16384 + quad * 8;
    f32x4 acc[8];
#pragma unroll
    for (int ct = 0; ct < 8; ct++) acc[ct] = (f32x4){0.f, 0.f, 0.f, 0.f};
#pragma unroll
    for (int ks = 0; ks < 4; ks++) {
        bf16x8 a = *(const bf16x8*)(yrow + ks * 32);
#pragma unroll
        for (int ct = 0; ct < 8; ct++) {
            bf16x8 b = *(const bf16x8*)(Wh + (ct * 16 + n16) * 128 + ks * 32);
            acc[ct] = __builtin_amdgcn_mfma_f32_16x16x32_bf16(a, b, acc[ct], 0, 0, 0);
        }
    }
#pragma unroll
    for (int ct = 0; ct < 8; ct++) {
        int c = h * 128 + ct * 16 + n16;
        float bias = b1[c];
#pragma unroll
        for (int r = 0; r < 4; r++) {
            int node = nb + w * 16 + quad * 4 + r;
            if (node < N) {
                float v = acc[ct][r] + bias;
                v = v > 0.f ? v : expm1f(v);
                hbuf_b[(size_t)node * 1024 + c] = f2bf(v);
            }
        }
    }
}

// ---------------- l2_transform (MFMA): h2 = hbuf @ W2, alpha_s2/ad2 -----------------

__global__ __launch_bounds__(256) void l2_transform(
    const unsigned short* __restrict__ hbuf_b, const unsigned short* __restrict__ W2bT,
    const float* __restrict__ a_src2, const float* __restrict__ a_dst2,
    float* __restrict__ h2, float* __restrict__ as2, float* __restrict__ ad2, int N) {
    int nb = blockIdx.x * 16;
    int ct = threadIdx.x >> 6;
    int lane = threadIdx.x & 63;
    int n16 = lane & 15, quad = lane >> 4;
    int node_a = nb + n16;
    const unsigned short* arow =
        hbuf_b + (size_t)(node_a < N ? node_a : N - 1) * 1024 + quad * 8;
    const unsigned short* brow = W2bT + (size_t)(ct * 16 + n16) * 1024 + quad * 8;
    f32x4 acc = (f32x4){0.f, 0.f, 0.f, 0.f};
#pragma unroll 8
    for (int ks = 0; ks < 32; ks++) {
        bf16x8 a = *(const bf16x8*)(arow + ks * 32);
        bf16x8 b = *(const bf16x8*)(brow + ks * 32);
        acc = __builtin_amdgcn_mfma_f32_16x16x32_bf16(a, b, acc, 0, 0, 0);
    }
    int c = ct * 16 + n16;
    float asc = a_src2[c], adc = a_dst2[c];
    float pav[4], pdv[4];
#pragma unroll
    for (int r = 0; r < 4; r++) {
        int node = nb + quad * 4 + r;
        if (node < N) h2[(size_t)node * 64 + c] = acc[r];
        pav[r] = acc[r] * asc;
        pdv[r] = acc[r] * adc;
#pragma unroll
        for (int mm = 1; mm <= 8; mm <<= 1) {
            pav[r] += __shfl_xor(pav[r], mm);
            pdv[r] += __shfl_xor(pdv[r], mm);
        }
    }
    __shared__ float sA[4][16], sD[4][16];
    if (n16 == 0) {
#pragma unroll
        for (int r = 0; r < 4; r++) {
            sA[ct][quad * 4 + r] = pav[r];
            sD[ct][quad * 4 + r] = pdv[r];
        }
    }
    __syncthreads();
    if (threadIdx.x < 16) {
        int node = nb + threadIdx.x;
        if (node < N) {
            as2[node] = sA[0][threadIdx.x] + sA[1][threadIdx.x] + sA[2][threadIdx.x] + sA[3][threadIdx.x];
            ad2[node] = sD[0][threadIdx.x] + sD[1][threadIdx.x] + sD[2][threadIdx.x] + sD[3][threadIdx.x];
        }
    }
}

// ---------------- w2k: edge-parallel layer-2 softmax numerators ----------------

__global__ __launch_bounds__(256) void w2k(
    const int* __restrict__ srcs, const int* __restrict__ dsts,
    const float* __restrict__ as2, const float* __restrict__ ad2,
    float* __restrict__ w2buf, float* __restrict__ wsum2, int M) {
    int e = blockIdx.x * 256 + threadIdx.x;
    if (e >= M) return;
    int s = srcs[e], d = dsts[e];
    float w = __expf(leaky(as2[s] + ad2[d]));
    w2buf[e] = w;
    atomicAdd(&wsum2[d], w);
}

// ---------------- l2_gather: wave per node, lane = channel --------------------

__global__ __launch_bounds__(256) void l2_gather(
    const float* __restrict__ h2, const float* __restrict__ w2buf,
    const float* __restrict__ wsum2, const float* __restrict__ b2,
    const int* __restrict__ offsets, const int* __restrict__ srcs,
    float* __restrict__ out, int N) {
    int n = blockIdx.x * 4 + (threadIdx.x >> 6);
    if (n >= N) return;
    int lane = threadIdx.x & 63;
    int beg = offsets[n];
    int deg = offsets[n + 1] - beg;
    float acc = 0.f;
    int i = 0;
    for (; i + 4 <= deg; i += 4) {
        int s0 = srcs[beg + i],     s1 = srcs[beg + i + 1];
        int s2 = srcs[beg + i + 2], s3 = srcs[beg + i + 3];
        float w0 = w2buf[beg + i],     w1 = w2buf[beg + i + 1];
        float w2 = w2buf[beg + i + 2], w3 = w2buf[beg + i + 3];
        float v0 = h2[(size_t)s0 * 64 + lane];
        float v1 = h2[(size_t)s1 * 64 + lane];
        float v2 = h2[(size_t)s2 * 64 + lane];
        float v3 = h2[(size_t)s3 * 64 + lane];
        acc = fmaf(w0, v0, acc);
        acc = fmaf(w1, v1, acc);
        acc = fmaf(w2, v2, acc);
        acc = fmaf(w3, v3, acc);
    }
    for (; i < deg; i++) {
        int s = srcs[beg + i];
        acc = fmaf(w2buf[beg + i], h2[(size_t)s * 64 + lane], acc);
    }
    out[(size_t)n * 64 + lane] = acc / (wsum2[n] + 1e-16f) + b2[lane];
}

// ---------------- launch ----------------

static inline size_t align_up(size_t v, size_t a) { return (v + a - 1) / a * a; }

extern "C" void kernel_launch(void* const* d_in, const int* in_sizes, int n_in,
                              void* d_out, int out_size, void* d_ws, size_t ws_size,
                              hipStream_t stream) {
    const float* x      = (const float*)d_in[0];
    const int*   ei     = (const int*)d_in[1];
    const float* W1     = (const float*)d_in[2];
    const float* a_src1 = (const float*)d_in[3];
    const float* a_dst1 = (const float*)d_in[4];
    const float* b1     = (const float*)d_in[5];
    const float* W2     = (const float*)d_in[6];
    const float* a_src2 = (const float*)d_in[7];
    const float* a_dst2 = (const float*)d_in[8];
    const float* b2     = (const float*)d_in[9];
    float* out = (float*)d_out;

    int N = in_sizes[0] / 128;
    int E = in_sizes[1] / 2;
    int M = E + N;

    char* p = (char*)d_ws;
    size_t off = 0;
    auto carve = [&](size_t bytes) {
        void* r = p + off;
        off = align_up(off + bytes, 256);
        return r;
    };
    // zero-init region: counts + wsum1 + wsum2 (carved adjacently)
    int*            counts  = (int*)carve((size_t)N * 4);
    float*          wsum1   = (float*)carve((size_t)N * 8 * 4);
    float*          wsum2   = (float*)carve((size_t)N * 4);
    size_t zero_span = off;
    int*            offsets = (int*)carve((size_t)(N + 1) * 4);
    int*            cursor  = (int*)carve((size_t)N * 4);
    int*            srcs    = (int*)carve((size_t)M * 4);
    int*            dsts    = (int*)carve((size_t)M * 4);
    float*          As      = (float*)carve(1024 * 4);
    float*          Ad      = (float*)carve(1024 * 4);
    float*          as1     = (float*)carve((size_t)N * 8 * 4);
    float*          ad1     = (float*)carve((size_t)N * 8 * 4);
    float*          as2     = (float*)carve((size_t)N * 4);
    float*          ad2     = (float*)carve((size_t)N * 4);
    float*          h2      = (float*)carve((size_t)N * 64 * 4);
    float*          wbuf    = (float*)carve((size_t)M * 8 * 4);
    float*          w2buf   = (float*)carve((size_t)M * 4);
    unsigned short* W1bT    = (unsigned short*)carve((size_t)8 * 128 * 128 * 2);
    unsigned short* W2bT    = (unsigned short*)carve((size_t)64 * 1024 * 2);
    unsigned short* y_b     = (unsigned short*)carve((size_t)N * 1024 * 2);
    unsigned short* hbuf_b  = (unsigned short*)carve((size_t)N * 1024 * 2);
    (void)ws_size; // ~60 MB

    hipMemsetAsync(counts, 0, zero_span, stream);
    prep_all<<<196, 256, 0, stream>>>(W1, a_src1, a_dst1, W2, As, Ad, W1bT, W2bT);
    alpha1_kernel<<<(N + 31) / 32, 256, 0, stream>>>(x, As, Ad, as1, ad1, N);
    count_kernel<<<(M + 255) / 256, 256, 0, stream>>>(ei, counts, E, N);
    scan_kernel<<<1, 1024, 0, stream>>>(counts, offsets, cursor, N);
    fill_kernel<<<(M + 255) / 256, 256, 0, stream>>>(ei, cursor, srcs, dsts, E, N);
    w1k<<<(M + 255) / 256, 256, 0, stream>>>(srcs, dsts, as1, ad1, wbuf, wsum1, M);
    l1_gather<<<(N + 3) / 4, 256, 0, stream>>>(x, wbuf, wsum1, offsets, srcs, y_b, N);
    l1_gemm<<<((N + 63) / 64) * 8, 256, 0, stream>>>(y_b, W1bT, b1, hbuf_b, N);
    l2_transform<<<(N + 15) / 16, 256, 0, stream>>>(hbuf_b, W2bT, a_src2, a_dst2, h2, as2, ad2, N);
    w2k<<<(M + 255) / 256, 256, 0, stream>>>(srcs, dsts, as2, ad2, w2buf, wsum2, M);
    l2_gather<<<(N + 3) / 4, 256, 0, stream>>>(h2, w2buf, wsum2, b2, offsets, srcs, out, N);
}

// Round 12
// 225.908 us; speedup vs baseline: 1.4698x; 1.4698x over previous
//
#include <hip/hip_runtime.h>
#include <math.h>

// GAT 2-layer: N=10000, E=160000 (+N self loops), IN=128, H1=8, C1=128, OUT=64.
// R12: R11 minus the atomics -- softmax denominators accumulated in-register
//      inside the gather kernels (every lane already reads every weight).
//      w1k/w2k are pure streaming exp kernels. GEMMs stay bf16 MFMA.

#define NEG_SLOPE 0.2f

typedef short bf16x8 __attribute__((ext_vector_type(8)));
typedef float f32x4 __attribute__((ext_vector_type(4)));

__device__ __forceinline__ float leaky(float v) { return v >= 0.0f ? v : NEG_SLOPE * v; }

__device__ __forceinline__ unsigned short f2bf(float f) {
    unsigned u = __float_as_uint(f);
    u += 0x7FFFu + ((u >> 16) & 1u);   // round-to-nearest-even
    return (unsigned short)(u >> 16);
}

// ---------------- CSR build ----------------

__global__ void count_kernel(const int* __restrict__ ei, int* __restrict__ counts, int E, int N) {
    int i = blockIdx.x * blockDim.x + threadIdx.x;
    int M = E + N;
    if (i >= M) return;
    int dst = (i < E) ? ei[E + i] : (i - E);   // self-loop tail
    atomicAdd(&counts[dst], 1);
}

// single-block scan: serial per-thread sums + wave shuffle scan (2 barriers)
__global__ __launch_bounds__(1024) void scan_kernel(
    const int* __restrict__ counts, int* __restrict__ offsets,
    int* __restrict__ cursor, int N) {
    __shared__ int wsum[16];
    int t = threadIdx.x;
    int per = (N + 1023) / 1024;
    int base = t * per;
    int s = 0;
    for (int j = 0; j < per; j++) {
        int idx = base + j;
        if (idx < N) s += counts[idx];
    }
    int lane = t & 63, wid = t >> 6;
    int inc = s;
#pragma unroll
    for (int off = 1; off <= 32; off <<= 1) {
        int v = __shfl_up(inc, off);
        if (lane >= off) inc += v;
    }
    if (lane == 63) wsum[wid] = inc;
    __syncthreads();
    if (t < 16) {
        int v = wsum[t];
        int iv = v;
#pragma unroll
        for (int off = 1; off <= 8; off <<= 1) {
            int u = __shfl_up(iv, off);
            if (t >= off) iv += u;
        }
        wsum[t] = iv - v;   // exclusive
    }
    __syncthreads();
    int run = wsum[wid] + inc - s;
    for (int j = 0; j < per; j++) {
        int idx = base + j;
        if (idx < N) {
            offsets[idx] = run;
            cursor[idx] = run;
            run += counts[idx];
        }
    }
    if (t == 1023) offsets[N] = run;
}

__global__ void fill_kernel(const int* __restrict__ ei, int* __restrict__ cursor,
                            int* __restrict__ srcs, int* __restrict__ dsts, int E, int N) {
    int i = blockIdx.x * blockDim.x + threadIdx.x;
    int M = E + N;
    if (i >= M) return;
    int src, dst;
    if (i < E) { src = ei[i]; dst = ei[E + i]; }
    else       { src = dst = i - E; }
    int pos = atomicAdd(&cursor[dst], 1);
    srcs[pos] = src;
    dsts[pos] = dst;
}

// ---------------- prep_all: As/Ad + W1->W1bT [h][c][k] bf16 + W2->W2bT [c][k] bf16 ---

__global__ __launch_bounds__(256) void prep_all(
    const float* __restrict__ W1, const float* __restrict__ a_src1,
    const float* __restrict__ a_dst1, const float* __restrict__ W2,
    float* __restrict__ As, float* __restrict__ Ad,
    unsigned short* __restrict__ W1bT, unsigned short* __restrict__ W2bT) {
    int b = blockIdx.x;
    __shared__ unsigned short tile[32][33];
    if (b < 4) {
        int i = b * 256 + threadIdx.x;   // 0..1023
        int k = i >> 3, h = i & 7;
        float ss = 0.f, sd = 0.f;
        for (int c = 0; c < 128; c += 4) {
            float4 w = *(const float4*)(W1 + (size_t)k * 1024 + h * 128 + c);
            float4 a = *(const float4*)(a_src1 + h * 128 + c);
            float4 d = *(const float4*)(a_dst1 + h * 128 + c);
            ss += w.x * a.x + w.y * a.y + w.z * a.z + w.w * a.w;
            sd += w.x * d.x + w.y * d.y + w.z * d.z + w.w * d.w;
        }
        As[k * 8 + h] = ss;
        Ad[k * 8 + h] = sd;
    } else if (b < 132) {
        int bb = b - 4;
        int kt = bb & 3, hct = bb >> 2;
        int j = threadIdx.x & 31;
        int i0 = threadIdx.x >> 5;
        for (int i = i0; i < 32; i += 8)
            tile[i][j] = f2bf(W1[(size_t)(kt * 32 + i) * 1024 + hct * 32 + j]);
        __syncthreads();
        for (int i = i0; i < 32; i += 8) {
            int hc = hct * 32 + i, k = kt * 32 + j;
            int h = hc >> 7, c = hc & 127;
            W1bT[h * 16384 + c * 128 + k] = tile[j][i];
        }
    } else {
        int bb = b - 132;
        int kt = bb & 31, ctile = bb >> 5;
        int j = threadIdx.x & 31;
        int i0 = threadIdx.x >> 5;
        for (int i = i0; i < 32; i += 8)
            tile[i][j] = f2bf(W2[(size_t)(kt * 32 + i) * 64 + ctile * 32 + j]);
        __syncthreads();
        for (int i = i0; i < 32; i += 8)
            W2bT[(size_t)(ctile * 32 + i) * 1024 + kt * 32 + j] = tile[j][i];
    }
}

// ---------------- alpha1: as1/ad1 = x @ As / Ad  [N,8] ----------------

__global__ __launch_bounds__(256) void alpha1_kernel(
    const float* __restrict__ x, const float* __restrict__ As, const float* __restrict__ Ad,
    float* __restrict__ as1, float* __restrict__ ad1, int N) {
    __shared__ float sAs[1024], sAd[1024];
    int t = threadIdx.x;
    {
        int i = t * 4;
        *(float4*)(sAs + i) = *(const float4*)(As + i);
        *(float4*)(sAd + i) = *(const float4*)(Ad + i);
    }
    __syncthreads();
    int node = blockIdx.x * 32 + (t >> 3);
    int h = t & 7;
    if (node >= N) return;
    float accs = 0.f, accd = 0.f;
    for (int k = 0; k < 128; k += 4) {
        float4 xv = *(const float4*)(x + (size_t)node * 128 + k);
        accs += xv.x * sAs[k * 8 + h] + xv.y * sAs[(k + 1) * 8 + h]
              + xv.z * sAs[(k + 2) * 8 + h] + xv.w * sAs[(k + 3) * 8 + h];
        accd += xv.x * sAd[k * 8 + h] + xv.y * sAd[(k + 1) * 8 + h]
              + xv.z * sAd[(k + 2) * 8 + h] + xv.w * sAd[(k + 3) * 8 + h];
    }
    as1[node * 8 + h] = accs;
    ad1[node * 8 + h] = accd;
}

// ---------------- w1k: edge-parallel layer-1 softmax numerators (no atomics) ----

__global__ __launch_bounds__(256) void w1k(
    const int* __restrict__ srcs, const int* __restrict__ dsts,
    const float* __restrict__ as1, const float* __restrict__ ad1,
    float* __restrict__ wbuf, int M) {
    int e = blockIdx.x * 256 + threadIdx.x;
    if (e >= M) return;
    int s = srcs[e], d = dsts[e];
    float4 a0 = *(const float4*)(as1 + (size_t)s * 8);
    float4 a1 = *(const float4*)(as1 + (size_t)s * 8 + 4);
    float4 b0 = *(const float4*)(ad1 + (size_t)d * 8);
    float4 b1 = *(const float4*)(ad1 + (size_t)d * 8 + 4);
    float4 w0, w1;
    w0.x = __expf(leaky(a0.x + b0.x));
    w0.y = __expf(leaky(a0.y + b0.y));
    w0.z = __expf(leaky(a0.z + b0.z));
    w0.w = __expf(leaky(a0.w + b0.w));
    w1.x = __expf(leaky(a1.x + b1.x));
    w1.y = __expf(leaky(a1.y + b1.y));
    w1.z = __expf(leaky(a1.z + b1.z));
    w1.w = __expf(leaky(a1.w + b1.w));
    *(float4*)(wbuf + (size_t)e * 8)     = w0;
    *(float4*)(wbuf + (size_t)e * 8 + 4) = w1;
}

// ---------------- l1_gather: wave per node, pure gather, in-register wsum --------
// Lane owns channels {lane*2, lane*2+1} of ALL 8 heads: x row loaded once/wave.

__global__ __launch_bounds__(256) void l1_gather(
    const float* __restrict__ x, const float* __restrict__ wbuf,
    const int* __restrict__ offsets, const int* __restrict__ srcs,
    unsigned short* __restrict__ y_b, int N) {
    int n = blockIdx.x * 4 + (threadIdx.x >> 6);
    if (n >= N) return;
    int lane = threadIdx.x & 63;
    int beg = offsets[n];
    int deg = offsets[n + 1] - beg;
    float2 acc[8];
#pragma unroll
    for (int h = 0; h < 8; h++) acc[h] = make_float2(0.f, 0.f);
    float4 ws0 = make_float4(0.f, 0.f, 0.f, 0.f);
    float4 ws1 = make_float4(0.f, 0.f, 0.f, 0.f);
    const float* xb = x + lane * 2;
#define L1G_BODY(I)                                                              \
    {                                                                            \
        int s_ = srcs[beg + (I)];                                                \
        float4 w0_ = *(const float4*)(wbuf + (size_t)(beg + (I)) * 8);           \
        float4 w1_ = *(const float4*)(wbuf + (size_t)(beg + (I)) * 8 + 4);       \
        float2 xv_ = *(const float2*)(xb + (size_t)s_ * 128);                    \
        ws0.x += w0_.x; ws0.y += w0_.y; ws0.z += w0_.z; ws0.w += w0_.w;          \
        ws1.x += w1_.x; ws1.y += w1_.y; ws1.z += w1_.z; ws1.w += w1_.w;          \
        acc[0].x = fmaf(w0_.x, xv_.x, acc[0].x); acc[0].y = fmaf(w0_.x, xv_.y, acc[0].y); \
        acc[1].x = fmaf(w0_.y, xv_.x, acc[1].x); acc[1].y = fmaf(w0_.y, xv_.y, acc[1].y); \
        acc[2].x = fmaf(w0_.z, xv_.x, acc[2].x); acc[2].y = fmaf(w0_.z, xv_.y, acc[2].y); \
        acc[3].x = fmaf(w0_.w, xv_.x, acc[3].x); acc[3].y = fmaf(w0_.w, xv_.y, acc[3].y); \
        acc[4].x = fmaf(w1_.x, xv_.x, acc[4].x); acc[4].y = fmaf(w1_.x, xv_.y, acc[4].y); \
        acc[5].x = fmaf(w1_.y, xv_.x, acc[5].x); acc[5].y = fmaf(w1_.y, xv_.y, acc[5].y); \
        acc[6].x = fmaf(w1_.z, xv_.x, acc[6].x); acc[6].y = fmaf(w1_.z, xv_.y, acc[6].y); \
        acc[7].x = fmaf(w1_.w, xv_.x, acc[7].x); acc[7].y = fmaf(w1_.w, xv_.y, acc[7].y); \
    }
    int i = 0;
    for (; i + 4 <= deg; i += 4) {       // 4 edges in flight
        L1G_BODY(i) L1G_BODY(i + 1) L1G_BODY(i + 2) L1G_BODY(i + 3)
    }
    for (; i < deg; i++) { L1G_BODY(i) }
#undef L1G_BODY
    float inv[8] = {1.f / (ws0.x + 1e-16f), 1.f / (ws0.y + 1e-16f),
                    1.f / (ws0.z + 1e-16f), 1.f / (ws0.w + 1e-16f),
                    1.f / (ws1.x + 1e-16f), 1.f / (ws1.y + 1e-16f),
                    1.f / (ws1.z + 1e-16f), 1.f / (ws1.w + 1e-16f)};
    unsigned short* dst = y_b + (size_t)n * 1024 + lane * 2;
#pragma unroll
    for (int h = 0; h < 8; h++) {
        unsigned lo = f2bf(acc[h].x * inv[h]);
        unsigned hi = f2bf(acc[h].y * inv[h]);
        *(unsigned*)(dst + h * 128) = lo | (hi << 16);   // coalesced per head
    }
}

// ---------------- l1_gemm (MFMA): hbuf_b = ELU(per-head y @ W1h + b1), bf16 out ----

__global__ __launch_bounds__(256) void l1_gemm(
    const unsigned short* __restrict__ y_b, const unsigned short* __restrict__ W1bT,
    const float* __restrict__ b1, unsigned short* __restrict__ hbuf_b, int N) {
    int h  = blockIdx.x & 7;
    int nb = (blockIdx.x >> 3) * 64;
    int w  = threadIdx.x >> 6;
    int lane = threadIdx.x & 63;
    int n16 = lane & 15, quad = lane >> 4;
    int node_a = nb + w * 16 + n16;
    const unsigned short* yrow =
        y_b + (size_t)(node_a < N ? node_a : 0) * 1024 + h * 128 + quad * 8;
    const unsigned short* Wh = W1bT + h * 16384 + quad * 8;
    f32x4 acc[8];
#pragma unroll
    for (int ct = 0; ct < 8; ct++) acc[ct] = (f32x4){0.f, 0.f, 0.f, 0.f};
#pragma unroll
    for (int ks = 0; ks < 4; ks++) {
        bf16x8 a = *(const bf16x8*)(yrow + ks * 32);
#pragma unroll
        for (int ct = 0; ct < 8; ct++) {
            bf16x8 b = *(const bf16x8*)(Wh + (ct * 16 + n16) * 128 + ks * 32);
            acc[ct] = __builtin_amdgcn_mfma_f32_16x16x32_bf16(a, b, acc[ct], 0, 0, 0);
        }
    }
#pragma unroll
    for (int ct = 0; ct < 8; ct++) {
        int c = h * 128 + ct * 16 + n16;
        float bias = b1[c];
#pragma unroll
        for (int r = 0; r < 4; r++) {
            int node = nb + w * 16 + quad * 4 + r;
            if (node < N) {
                float v = acc[ct][r] + bias;
                v = v > 0.f ? v : expm1f(v);
                hbuf_b[(size_t)node * 1024 + c] = f2bf(v);
            }
        }
    }
}

// ---------------- l2_transform (MFMA): h2 = hbuf @ W2, alpha_s2/ad2 -----------------

__global__ __launch_bounds__(256) void l2_transform(
    const unsigned short* __restrict__ hbuf_b, const unsigned short* __restrict__ W2bT,
    const float* __restrict__ a_src2, const float* __restrict__ a_dst2,
    float* __restrict__ h2, float* __restrict__ as2, float* __restrict__ ad2, int N) {
    int nb = blockIdx.x * 16;
    int ct = threadIdx.x >> 6;
    int lane = threadIdx.x & 63;
    int n16 = lane & 15, quad = lane >> 4;
    int node_a = nb + n16;
    const unsigned short* arow =
        hbuf_b + (size_t)(node_a < N ? node_a : N - 1) * 1024 + quad * 8;
    const unsigned short* brow = W2bT + (size_t)(ct * 16 + n16) * 1024 + quad * 8;
    f32x4 acc = (f32x4){0.f, 0.f, 0.f, 0.f};
#pragma unroll 8
    for (int ks = 0; ks < 32; ks++) {
        bf16x8 a = *(const bf16x8*)(arow + ks * 32);
        bf16x8 b = *(const bf16x8*)(brow + ks * 32);
        acc = __builtin_amdgcn_mfma_f32_16x16x32_bf16(a, b, acc, 0, 0, 0);
    }
    int c = ct * 16 + n16;
    float asc = a_src2[c], adc = a_dst2[c];
    float pav[4], pdv[4];
#pragma unroll
    for (int r = 0; r < 4; r++) {
        int node = nb + quad * 4 + r;
        if (node < N) h2[(size_t)node * 64 + c] = acc[r];
        pav[r] = acc[r] * asc;
        pdv[r] = acc[r] * adc;
#pragma unroll
        for (int mm = 1; mm <= 8; mm <<= 1) {
            pav[r] += __shfl_xor(pav[r], mm);
            pdv[r] += __shfl_xor(pdv[r], mm);
        }
    }
    __shared__ float sA[4][16], sD[4][16];
    if (n16 == 0) {
#pragma unroll
        for (int r = 0; r < 4; r++) {
            sA[ct][quad * 4 + r] = pav[r];
            sD[ct][quad * 4 + r] = pdv[r];
        }
    }
    __syncthreads();
    if (threadIdx.x < 16) {
        int node = nb + threadIdx.x;
        if (node < N) {
            as2[node] = sA[0][threadIdx.x] + sA[1][threadIdx.x] + sA[2][threadIdx.x] + sA[3][threadIdx.x];
            ad2[node] = sD[0][threadIdx.x] + sD[1][threadIdx.x] + sD[2][threadIdx.x] + sD[3][threadIdx.x];
        }
    }
}

// ---------------- w2k: edge-parallel layer-2 softmax numerators (no atomics) ----

__global__ __launch_bounds__(256) void w2k(
    const int* __restrict__ srcs, const int* __restrict__ dsts,
    const float* __restrict__ as2, const float* __restrict__ ad2,
    float* __restrict__ w2buf, int M) {
    int e = blockIdx.x * 256 + threadIdx.x;
    if (e >= M) return;
    int s = srcs[e], d = dsts[e];
    w2buf[e] = __expf(leaky(as2[s] + ad2[d]));
}

// ---------------- l2_gather: wave per node, lane = channel, in-register wsum -----

__global__ __launch_bounds__(256) void l2_gather(
    const float* __restrict__ h2, const float* __restrict__ w2buf,
    const float* __restrict__ b2, const int* __restrict__ offsets,
    const int* __restrict__ srcs, float* __restrict__ out, int N) {
    int n = blockIdx.x * 4 + (threadIdx.x >> 6);
    if (n >= N) return;
    int lane = threadIdx.x & 63;
    int beg = offsets[n];
    int deg = offsets[n + 1] - beg;
    float acc = 0.f, wsum = 0.f;
    int i = 0;
    for (; i + 4 <= deg; i += 4) {
        int s0 = srcs[beg + i],     s1 = srcs[beg + i + 1];
        int s2 = srcs[beg + i + 2], s3 = srcs[beg + i + 3];
        float w0 = w2buf[beg + i],     w1 = w2buf[beg + i + 1];
        float w2 = w2buf[beg + i + 2], w3 = w2buf[beg + i + 3];
        float v0 = h2[(size_t)s0 * 64 + lane];
        float v1 = h2[(size_t)s1 * 64 + lane];
        float v2 = h2[(size_t)s2 * 64 + lane];
        float v3 = h2[(size_t)s3 * 64 + lane];
        wsum += w0 + w1 + w2 + w3;
        acc = fmaf(w0, v0, acc);
        acc = fmaf(w1, v1, acc);
        acc = fmaf(w2, v2, acc);
        acc = fmaf(w3, v3, acc);
    }
    for (; i < deg; i++) {
        int s = srcs[beg + i];
        float w = w2buf[beg + i];
        wsum += w;
        acc = fmaf(w, h2[(size_t)s * 64 + lane], acc);
    }
    out[(size_t)n * 64 + lane] = acc / (wsum + 1e-16f) + b2[lane];
}

// ---------------- launch ----------------

static inline size_t align_up(size_t v, size_t a) { return (v + a - 1) / a * a; }

extern "C" void kernel_launch(void* const* d_in, const int* in_sizes, int n_in,
                              void* d_out, int out_size, void* d_ws, size_t ws_size,
                              hipStream_t stream) {
    const float* x      = (const float*)d_in[0];
    const int*   ei     = (const int*)d_in[1];
    const float* W1     = (const float*)d_in[2];
    const float* a_src1 = (const float*)d_in[3];
    const float* a_dst1 = (const float*)d_in[4];
    const float* b1     = (const float*)d_in[5];
    const float* W2     = (const float*)d_in[6];
    const float* a_src2 = (const float*)d_in[7];
    const float* a_dst2 = (const float*)d_in[8];
    const float* b2     = (const float*)d_in[9];
    float* out = (float*)d_out;

    int N = in_sizes[0] / 128;
    int E = in_sizes[1] / 2;
    int M = E + N;

    char* p = (char*)d_ws;
    size_t off = 0;
    auto carve = [&](size_t bytes) {
        void* r = p + off;
        off = align_up(off + bytes, 256);
        return r;
    };
    int*            counts  = (int*)carve((size_t)N * 4);
    int*            offsets = (int*)carve((size_t)(N + 1) * 4);
    int*            cursor  = (int*)carve((size_t)N * 4);
    int*            srcs    = (int*)carve((size_t)M * 4);
    int*            dsts    = (int*)carve((size_t)M * 4);
    float*          As      = (float*)carve(1024 * 4);
    float*          Ad      = (float*)carve(1024 * 4);
    float*          as1     = (float*)carve((size_t)N * 8 * 4);
    float*          ad1     = (float*)carve((size_t)N * 8 * 4);
    float*          as2     = (float*)carve((size_t)N * 4);
    float*          ad2     = (float*)carve((size_t)N * 4);
    float*          h2      = (float*)carve((size_t)N * 64 * 4);
    float*          wbuf    = (float*)carve((size_t)M * 8 * 4);
    float*          w2buf   = (float*)carve((size_t)M * 4);
    unsigned short* W1bT    = (unsigned short*)carve((size_t)8 * 128 * 128 * 2);
    unsigned short* W2bT    = (unsigned short*)carve((size_t)64 * 1024 * 2);
    unsigned short* y_b     = (unsigned short*)carve((size_t)N * 1024 * 2);
    unsigned short* hbuf_b  = (unsigned short*)carve((size_t)N * 1024 * 2);
    (void)ws_size; // ~60 MB

    hipMemsetAsync(counts, 0, (size_t)N * 4, stream);
    prep_all<<<196, 256, 0, stream>>>(W1, a_src1, a_dst1, W2, As, Ad, W1bT, W2bT);
    alpha1_kernel<<<(N + 31) / 32, 256, 0, stream>>>(x, As, Ad, as1, ad1, N);
    count_kernel<<<(M + 255) / 256, 256, 0, stream>>>(ei, counts, E, N);
    scan_kernel<<<1, 1024, 0, stream>>>(counts, offsets, cursor, N);
    fill_kernel<<<(M + 255) / 256, 256, 0, stream>>>(ei, cursor, srcs, dsts, E, N);
    w1k<<<(M + 255) / 256, 256, 0, stream>>>(srcs, dsts, as1, ad1, wbuf, M);
    l1_gather<<<(N + 3) / 4, 256, 0, stream>>>(x, wbuf, offsets, srcs, y_b, N);
    l1_gemm<<<((N + 63) / 64) * 8, 256, 0, stream>>>(y_b, W1bT, b1, hbuf_b, N);
    l2_transform<<<(N + 15) / 16, 256, 0, stream>>>(hbuf_b, W2bT, a_src2, a_dst2, h2, as2, ad2, N);
    w2k<<<(M + 255) / 256, 256, 0, stream>>>(srcs, dsts, as2, ad2, w2buf, M);
    l2_gather<<<(N + 3) / 4, 256, 0, stream>>>(h2, w2buf, b2, offsets, srcs, out, N);
}

// Round 13
// 210.663 us; speedup vs baseline: 1.5761x; 1.0724x over previous
//
#include <hip/hip_runtime.h>
#include <math.h>

// GAT 2-layer: N=10000, E=160000 (+N self loops), IN=128, H1=8, C1=128, OUT=64.
// R13: dispatch fusion -- 8 dispatches (was 12):
//   [memset] [prep+count] [alpha1+scan] [fill+w1] [l1_gather] [l1_gemm]
//   [l2_transform] [l2_gather(+w2 inline)]
// GEMMs stay bf16 MFMA (16x16x32, fp32 accumulate); softmax path fp32.

#define NEG_SLOPE 0.2f

typedef short bf16x8 __attribute__((ext_vector_type(8)));
typedef float f32x4 __attribute__((ext_vector_type(4)));

__device__ __forceinline__ float leaky(float v) { return v >= 0.0f ? v : NEG_SLOPE * v; }

__device__ __forceinline__ unsigned short f2bf(float f) {
    unsigned u = __float_as_uint(f);
    u += 0x7FFFu + ((u >> 16) & 1u);   // round-to-nearest-even
    return (unsigned short)(u >> 16);
}

// ---------------- kernel 1: prep (As/Ad, W1bT, W2bT) + edge count ----------------
// blocks 0..3: As/Ad; 4..131: W1 transpose; 132..195: W2 transpose; 196..: count.

__global__ __launch_bounds__(256) void prep_count(
    const float* __restrict__ W1, const float* __restrict__ a_src1,
    const float* __restrict__ a_dst1, const float* __restrict__ W2,
    const int* __restrict__ ei,
    float* __restrict__ As, float* __restrict__ Ad,
    unsigned short* __restrict__ W1bT, unsigned short* __restrict__ W2bT,
    int* __restrict__ counts, int E, int N) {
    int b = blockIdx.x;
    __shared__ unsigned short tile[32][33];
    if (b < 4) {
        int i = b * 256 + threadIdx.x;   // 0..1023
        int k = i >> 3, h = i & 7;
        float ss = 0.f, sd = 0.f;
        for (int c = 0; c < 128; c += 4) {
            float4 w = *(const float4*)(W1 + (size_t)k * 1024 + h * 128 + c);
            float4 a = *(const float4*)(a_src1 + h * 128 + c);
            float4 d = *(const float4*)(a_dst1 + h * 128 + c);
            ss += w.x * a.x + w.y * a.y + w.z * a.z + w.w * a.w;
            sd += w.x * d.x + w.y * d.y + w.z * d.z + w.w * d.w;
        }
        As[k * 8 + h] = ss;
        Ad[k * 8 + h] = sd;
    } else if (b < 132) {
        int bb = b - 4;
        int kt = bb & 3, hct = bb >> 2;
        int j = threadIdx.x & 31;
        int i0 = threadIdx.x >> 5;
        for (int i = i0; i < 32; i += 8)
            tile[i][j] = f2bf(W1[(size_t)(kt * 32 + i) * 1024 + hct * 32 + j]);
        __syncthreads();
        for (int i = i0; i < 32; i += 8) {
            int hc = hct * 32 + i, k = kt * 32 + j;
            int h = hc >> 7, c = hc & 127;
            W1bT[h * 16384 + c * 128 + k] = tile[j][i];
        }
    } else if (b < 196) {
        int bb = b - 132;
        int kt = bb & 31, ctile = bb >> 5;
        int j = threadIdx.x & 31;
        int i0 = threadIdx.x >> 5;
        for (int i = i0; i < 32; i += 8)
            tile[i][j] = f2bf(W2[(size_t)(kt * 32 + i) * 64 + ctile * 32 + j]);
        __syncthreads();
        for (int i = i0; i < 32; i += 8)
            W2bT[(size_t)(ctile * 32 + i) * 1024 + kt * 32 + j] = tile[j][i];
    } else {
        int i = (b - 196) * 256 + threadIdx.x;
        int M = E + N;
        if (i >= M) return;
        int dst = (i < E) ? ei[E + i] : (i - E);   // self-loop tail
        atomicAdd(&counts[dst], 1);
    }
}

// ---------------- kernel 2: alpha1 (blocks 0..nb_alpha-1) + scan (last block) -----
// 1024 threads. alpha1: 128 nodes/block. scan: serial sums + shuffle scan.

__global__ __launch_bounds__(1024) void alpha_scan(
    const float* __restrict__ x, const float* __restrict__ As, const float* __restrict__ Ad,
    float* __restrict__ as1, float* __restrict__ ad1,
    const int* __restrict__ counts, int* __restrict__ offsets,
    int* __restrict__ cursor, int N, int nb_alpha) {
    int t = threadIdx.x;
    if ((int)blockIdx.x < nb_alpha) {
        __shared__ float sAs[1024], sAd[1024];
        sAs[t] = As[t];
        sAd[t] = Ad[t];
        __syncthreads();
        int node = blockIdx.x * 128 + (t >> 3);
        int h = t & 7;
        if (node >= N) return;
        float accs = 0.f, accd = 0.f;
        for (int k = 0; k < 128; k += 4) {
            float4 xv = *(const float4*)(x + (size_t)node * 128 + k);
            accs += xv.x * sAs[k * 8 + h] + xv.y * sAs[(k + 1) * 8 + h]
                  + xv.z * sAs[(k + 2) * 8 + h] + xv.w * sAs[(k + 3) * 8 + h];
            accd += xv.x * sAd[k * 8 + h] + xv.y * sAd[(k + 1) * 8 + h]
                  + xv.z * sAd[(k + 2) * 8 + h] + xv.w * sAd[(k + 3) * 8 + h];
        }
        as1[node * 8 + h] = accs;
        ad1[node * 8 + h] = accd;
    } else {
        __shared__ int wsum[16];
        int per = (N + 1023) / 1024;
        int base = t * per;
        int s = 0;
        for (int j = 0; j < per; j++) {
            int idx = base + j;
            if (idx < N) s += counts[idx];
        }
        int lane = t & 63, wid = t >> 6;
        int inc = s;
#pragma unroll
        for (int off = 1; off <= 32; off <<= 1) {
            int v = __shfl_up(inc, off);
            if (lane >= off) inc += v;
        }
        if (lane == 63) wsum[wid] = inc;
        __syncthreads();
        if (t < 16) {
            int v = wsum[t];
            int iv = v;
#pragma unroll
            for (int off = 1; off <= 8; off <<= 1) {
                int u = __shfl_up(iv, off);
                if (t >= off) iv += u;
            }
            wsum[t] = iv - v;   // exclusive
        }
        __syncthreads();
        int run = wsum[wid] + inc - s;
        for (int j = 0; j < per; j++) {
            int idx = base + j;
            if (idx < N) {
                offsets[idx] = run;
                cursor[idx] = run;
                run += counts[idx];
            }
        }
        if (t == 1023) offsets[N] = run;
    }
}

// ---------------- kernel 3: fill CSR + inline layer-1 softmax numerators ---------

__global__ __launch_bounds__(256) void fill_w1(
    const int* __restrict__ ei, int* __restrict__ cursor,
    const float* __restrict__ as1, const float* __restrict__ ad1,
    int* __restrict__ srcs, float* __restrict__ wbuf, int E, int N) {
    int i = blockIdx.x * blockDim.x + threadIdx.x;
    int M = E + N;
    if (i >= M) return;
    int src, dst;
    if (i < E) { src = ei[i]; dst = ei[E + i]; }
    else       { src = dst = i - E; }
    int pos = atomicAdd(&cursor[dst], 1);
    srcs[pos] = src;
    float4 a0 = *(const float4*)(as1 + (size_t)src * 8);
    float4 a1 = *(const float4*)(as1 + (size_t)src * 8 + 4);
    float4 b0 = *(const float4*)(ad1 + (size_t)dst * 8);
    float4 b1 = *(const float4*)(ad1 + (size_t)dst * 8 + 4);
    float4 w0, w1;
    w0.x = __expf(leaky(a0.x + b0.x));
    w0.y = __expf(leaky(a0.y + b0.y));
    w0.z = __expf(leaky(a0.z + b0.z));
    w0.w = __expf(leaky(a0.w + b0.w));
    w1.x = __expf(leaky(a1.x + b1.x));
    w1.y = __expf(leaky(a1.y + b1.y));
    w1.z = __expf(leaky(a1.z + b1.z));
    w1.w = __expf(leaky(a1.w + b1.w));
    *(float4*)(wbuf + (size_t)pos * 8)     = w0;
    *(float4*)(wbuf + (size_t)pos * 8 + 4) = w1;
}

// ---------------- l1_gather: wave per node, pure gather, in-register wsum --------
// Lane owns channels {lane*2, lane*2+1} of ALL 8 heads: x row loaded once/wave.

__global__ __launch_bounds__(256) void l1_gather(
    const float* __restrict__ x, const float* __restrict__ wbuf,
    const int* __restrict__ offsets, const int* __restrict__ srcs,
    unsigned short* __restrict__ y_b, int N) {
    int n = blockIdx.x * 4 + (threadIdx.x >> 6);
    if (n >= N) return;
    int lane = threadIdx.x & 63;
    int beg = offsets[n];
    int deg = offsets[n + 1] - beg;
    float2 acc[8];
#pragma unroll
    for (int h = 0; h < 8; h++) acc[h] = make_float2(0.f, 0.f);
    float4 ws0 = make_float4(0.f, 0.f, 0.f, 0.f);
    float4 ws1 = make_float4(0.f, 0.f, 0.f, 0.f);
    const float* xb = x + lane * 2;
#define L1G_BODY(I)                                                              \
    {                                                                            \
        int s_ = srcs[beg + (I)];                                                \
        float4 w0_ = *(const float4*)(wbuf + (size_t)(beg + (I)) * 8);           \
        float4 w1_ = *(const float4*)(wbuf + (size_t)(beg + (I)) * 8 + 4);       \
        float2 xv_ = *(const float2*)(xb + (size_t)s_ * 128);                    \
        ws0.x += w0_.x; ws0.y += w0_.y; ws0.z += w0_.z; ws0.w += w0_.w;          \
        ws1.x += w1_.x; ws1.y += w1_.y; ws1.z += w1_.z; ws1.w += w1_.w;          \
        acc[0].x = fmaf(w0_.x, xv_.x, acc[0].x); acc[0].y = fmaf(w0_.x, xv_.y, acc[0].y); \
        acc[1].x = fmaf(w0_.y, xv_.x, acc[1].x); acc[1].y = fmaf(w0_.y, xv_.y, acc[1].y); \
        acc[2].x = fmaf(w0_.z, xv_.x, acc[2].x); acc[2].y = fmaf(w0_.z, xv_.y, acc[2].y); \
        acc[3].x = fmaf(w0_.w, xv_.x, acc[3].x); acc[3].y = fmaf(w0_.w, xv_.y, acc[3].y); \
        acc[4].x = fmaf(w1_.x, xv_.x, acc[4].x); acc[4].y = fmaf(w1_.x, xv_.y, acc[4].y); \
        acc[5].x = fmaf(w1_.y, xv_.x, acc[5].x); acc[5].y = fmaf(w1_.y, xv_.y, acc[5].y); \
        acc[6].x = fmaf(w1_.z, xv_.x, acc[6].x); acc[6].y = fmaf(w1_.z, xv_.y, acc[6].y); \
        acc[7].x = fmaf(w1_.w, xv_.x, acc[7].x); acc[7].y = fmaf(w1_.w, xv_.y, acc[7].y); \
    }
    int i = 0;
    for (; i + 4 <= deg; i += 4) {       // 4 edges in flight
        L1G_BODY(i) L1G_BODY(i + 1) L1G_BODY(i + 2) L1G_BODY(i + 3)
    }
    for (; i < deg; i++) { L1G_BODY(i) }
#undef L1G_BODY
    float inv[8] = {1.f / (ws0.x + 1e-16f), 1.f / (ws0.y + 1e-16f),
                    1.f / (ws0.z + 1e-16f), 1.f / (ws0.w + 1e-16f),
                    1.f / (ws1.x + 1e-16f), 1.f / (ws1.y + 1e-16f),
                    1.f / (ws1.z + 1e-16f), 1.f / (ws1.w + 1e-16f)};
    unsigned short* dst = y_b + (size_t)n * 1024 + lane * 2;
#pragma unroll
    for (int h = 0; h < 8; h++) {
        unsigned lo = f2bf(acc[h].x * inv[h]);
        unsigned hi = f2bf(acc[h].y * inv[h]);
        *(unsigned*)(dst + h * 128) = lo | (hi << 16);   // coalesced per head
    }
}

// ---------------- l1_gemm (MFMA): hbuf_b = ELU(per-head y @ W1h + b1), bf16 out ----

__global__ __launch_bounds__(256) void l1_gemm(
    const unsigned short* __restrict__ y_b, const unsigned short* __restrict__ W1bT,
    const float* __restrict__ b1, unsigned short* __restrict__ hbuf_b, int N) {
    int h  = blockIdx.x & 7;
    int nb = (blockIdx.x >> 3) * 64;
    int w  = threadIdx.x >> 6;
    int lane = threadIdx.x & 63;
    int n16 = lane & 15, quad = lane >> 4;
    int node_a = nb + w * 16 + n16;
    const unsigned short* yrow =
        y_b + (size_t)(node_a < N ? node_a : 0) * 1024 + h * 128 + quad * 8;
    const unsigned short* Wh = W1bT + h * 16384 + quad * 8;
    f32x4 acc[8];
#pragma unroll
    for (int ct = 0; ct < 8; ct++) acc[ct] = (f32x4){0.f, 0.f, 0.f, 0.f};
#pragma unroll
    for (int ks = 0; ks < 4; ks++) {
        bf16x8 a = *(const bf16x8*)(yrow + ks * 32);
#pragma unroll
        for (int ct = 0; ct < 8; ct++) {
            bf16x8 b = *(const bf16x8*)(Wh + (ct * 16 + n16) * 128 + ks * 32);
            acc[ct] = __builtin_amdgcn_mfma_f32_16x16x32_bf16(a, b, acc[ct], 0, 0, 0);
        }
    }
#pragma unroll
    for (int ct = 0; ct < 8; ct++) {
        int c = h * 128 + ct * 16 + n16;
        float bias = b1[c];
#pragma unroll
        for (int r = 0; r < 4; r++) {
            int node = nb + w * 16 + quad * 4 + r;
            if (node < N) {
                float v = acc[ct][r] + bias;
                v = v > 0.f ? v : expm1f(v);
                hbuf_b[(size_t)node * 1024 + c] = f2bf(v);
            }
        }
    }
}

// ---------------- l2_transform (MFMA): h2 = hbuf @ W2, alpha_s2/ad2 -----------------

__global__ __launch_bounds__(256) void l2_transform(
    const unsigned short* __restrict__ hbuf_b, const unsigned short* __restrict__ W2bT,
    const float* __restrict__ a_src2, const float* __restrict__ a_dst2,
    float* __restrict__ h2, float* __restrict__ as2, float* __restrict__ ad2, int N) {
    int nb = blockIdx.x * 16;
    int ct = threadIdx.x >> 6;
    int lane = threadIdx.x & 63;
    int n16 = lane & 15, quad = lane >> 4;
    int node_a = nb + n16;
    const unsigned short* arow =
        hbuf_b + (size_t)(node_a < N ? node_a : N - 1) * 1024 + quad * 8;
    const unsigned short* brow = W2bT + (size_t)(ct * 16 + n16) * 1024 + quad * 8;
    f32x4 acc = (f32x4){0.f, 0.f, 0.f, 0.f};
#pragma unroll 8
    for (int ks = 0; ks < 32; ks++) {
        bf16x8 a = *(const bf16x8*)(arow + ks * 32);
        bf16x8 b = *(const bf16x8*)(brow + ks * 32);
        acc = __builtin_amdgcn_mfma_f32_16x16x32_bf16(a, b, acc, 0, 0, 0);
    }
    int c = ct * 16 + n16;
    float asc = a_src2[c], adc = a_dst2[c];
    float pav[4], pdv[4];
#pragma unroll
    for (int r = 0; r < 4; r++) {
        int node = nb + quad * 4 + r;
        if (node < N) h2[(size_t)node * 64 + c] = acc[r];
        pav[r] = acc[r] * asc;
        pdv[r] = acc[r] * adc;
#pragma unroll
        for (int mm = 1; mm <= 8; mm <<= 1) {
            pav[r] += __shfl_xor(pav[r], mm);
            pdv[r] += __shfl_xor(pdv[r], mm);
        }
    }
    __shared__ float sA[4][16], sD[4][16];
    if (n16 == 0) {
#pragma unroll
        for (int r = 0; r < 4; r++) {
            sA[ct][quad * 4 + r] = pav[r];
            sD[ct][quad * 4 + r] = pdv[r];
        }
    }
    __syncthreads();
    if (threadIdx.x < 16) {
        int node = nb + threadIdx.x;
        if (node < N) {
            as2[node] = sA[0][threadIdx.x] + sA[1][threadIdx.x] + sA[2][threadIdx.x] + sA[3][threadIdx.x];
            ad2[node] = sD[0][threadIdx.x] + sD[1][threadIdx.x] + sD[2][threadIdx.x] + sD[3][threadIdx.x];
        }
    }
}

// ---------------- l2_gather: wave per node, inline weights, in-register wsum -----

__global__ __launch_bounds__(256) void l2_gather(
    const float* __restrict__ h2, const float* __restrict__ as2,
    const float* __restrict__ ad2, const float* __restrict__ b2,
    const int* __restrict__ offsets, const int* __restrict__ srcs,
    float* __restrict__ out, int N) {
    int n = blockIdx.x * 4 + (threadIdx.x >> 6);
    if (n >= N) return;
    int lane = threadIdx.x & 63;
    int beg = offsets[n];
    int deg = offsets[n + 1] - beg;
    float adn = ad2[n];
    float acc = 0.f, wsum = 0.f;
    int i = 0;
    for (; i + 4 <= deg; i += 4) {
        int s0 = srcs[beg + i],     s1 = srcs[beg + i + 1];
        int s2 = srcs[beg + i + 2], s3 = srcs[beg + i + 3];
        float w0 = __expf(leaky(as2[s0] + adn));   // same addr all lanes -> broadcast
        float w1 = __expf(leaky(as2[s1] + adn));
        float w2 = __expf(leaky(as2[s2] + adn));
        float w3 = __expf(leaky(as2[s3] + adn));
        float v0 = h2[(size_t)s0 * 64 + lane];
        float v1 = h2[(size_t)s1 * 64 + lane];
        float v2 = h2[(size_t)s2 * 64 + lane];
        float v3 = h2[(size_t)s3 * 64 + lane];
        wsum += w0 + w1 + w2 + w3;
        acc = fmaf(w0, v0, acc);
        acc = fmaf(w1, v1, acc);
        acc = fmaf(w2, v2, acc);
        acc = fmaf(w3, v3, acc);
    }
    for (; i < deg; i++) {
        int s = srcs[beg + i];
        float w = __expf(leaky(as2[s] + adn));
        wsum += w;
        acc = fmaf(w, h2[(size_t)s * 64 + lane], acc);
    }
    out[(size_t)n * 64 + lane] = acc / (wsum + 1e-16f) + b2[lane];
}

// ---------------- launch ----------------

static inline size_t align_up(size_t v, size_t a) { return (v + a - 1) / a * a; }

extern "C" void kernel_launch(void* const* d_in, const int* in_sizes, int n_in,
                              void* d_out, int out_size, void* d_ws, size_t ws_size,
                              hipStream_t stream) {
    const float* x      = (const float*)d_in[0];
    const int*   ei     = (const int*)d_in[1];
    const float* W1     = (const float*)d_in[2];
    const float* a_src1 = (const float*)d_in[3];
    const float* a_dst1 = (const float*)d_in[4];
    const float* b1     = (const float*)d_in[5];
    const float* W2     = (const float*)d_in[6];
    const float* a_src2 = (const float*)d_in[7];
    const float* a_dst2 = (const float*)d_in[8];
    const float* b2     = (const float*)d_in[9];
    float* out = (float*)d_out;

    int N = in_sizes[0] / 128;
    int E = in_sizes[1] / 2;
    int M = E + N;

    char* p = (char*)d_ws;
    size_t off = 0;
    auto carve = [&](size_t bytes) {
        void* r = p + off;
        off = align_up(off + bytes, 256);
        return r;
    };
    int*            counts  = (int*)carve((size_t)N * 4);
    int*            offsets = (int*)carve((size_t)(N + 1) * 4);
    int*            cursor  = (int*)carve((size_t)N * 4);
    int*            srcs    = (int*)carve((size_t)M * 4);
    float*          As      = (float*)carve(1024 * 4);
    float*          Ad      = (float*)carve(1024 * 4);
    float*          as1     = (float*)carve((size_t)N * 8 * 4);
    float*          ad1     = (float*)carve((size_t)N * 8 * 4);
    float*          as2     = (float*)carve((size_t)N * 4);
    float*          ad2     = (float*)carve((size_t)N * 4);
    float*          h2      = (float*)carve((size_t)N * 64 * 4);
    float*          wbuf    = (float*)carve((size_t)M * 8 * 4);
    unsigned short* W1bT    = (unsigned short*)carve((size_t)8 * 128 * 128 * 2);
    unsigned short* W2bT    = (unsigned short*)carve((size_t)64 * 1024 * 2);
    unsigned short* y_b     = (unsigned short*)carve((size_t)N * 1024 * 2);
    unsigned short* hbuf_b  = (unsigned short*)carve((size_t)N * 1024 * 2);
    (void)ws_size; // ~60 MB

    int nb_count = (M + 255) / 256;
    int nb_alpha = (N + 127) / 128;

    hipMemsetAsync(counts, 0, (size_t)N * 4, stream);
    prep_count<<<196 + nb_count, 256, 0, stream>>>(W1, a_src1, a_dst1, W2, ei,
                                                   As, Ad, W1bT, W2bT, counts, E, N);
    alpha_scan<<<nb_alpha + 1, 1024, 0, stream>>>(x, As, Ad, as1, ad1,
                                                  counts, offsets, cursor, N, nb_alpha);
    fill_w1<<<nb_count, 256, 0, stream>>>(ei, cursor, as1, ad1, srcs, wbuf, E, N);
    l1_gather<<<(N + 3) / 4, 256, 0, stream>>>(x, wbuf, offsets, srcs, y_b, N);
    l1_gemm<<<((N + 63) / 64) * 8, 256, 0, stream>>>(y_b, W1bT, b1, hbuf_b, N);
    l2_transform<<<(N + 15) / 16, 256, 0, stream>>>(hbuf_b, W2bT, a_src2, a_dst2, h2, as2, ad2, N);
    l2_gather<<<(N + 3) / 4, 256, 0, stream>>>(h2, as2, ad2, b2, offsets, srcs, out, N);
}

// Round 14
// 209.258 us; speedup vs baseline: 1.5867x; 1.0067x over previous
//
#include <hip/hip_runtime.h>
#include <math.h>

// GAT 2-layer: N=10000, E=160000 (+N self loops), IN=128, H1=8, C1=128, OUT=64.
// R14: (1) alpha LDS layout transposed+staggered (As_t[h*132+k]) -> conflict-free;
//      (2) l2_transform K-split x2 (grid 1252, 4.9 waves/SIMD) with LDS reduce,
//          alpha2 logits via 2-way atomicAdd.
// 8 dispatches; GEMMs bf16 MFMA (fp32 accumulate); softmax path fp32.

#define NEG_SLOPE 0.2f

typedef short bf16x8 __attribute__((ext_vector_type(8)));
typedef float f32x4 __attribute__((ext_vector_type(4)));

__device__ __forceinline__ float leaky(float v) { return v >= 0.0f ? v : NEG_SLOPE * v; }

__device__ __forceinline__ unsigned short f2bf(float f) {
    unsigned u = __float_as_uint(f);
    u += 0x7FFFu + ((u >> 16) & 1u);   // round-to-nearest-even
    return (unsigned short)(u >> 16);
}

// ---------------- kernel 1: prep (As_t/Ad_t, W1bT, W2bT) + edge count ----------------
// blocks 0..3: As_t/Ad_t; 4..131: W1 transpose; 132..195: W2 transpose; 196..: count.

__global__ __launch_bounds__(256) void prep_count(
    const float* __restrict__ W1, const float* __restrict__ a_src1,
    const float* __restrict__ a_dst1, const float* __restrict__ W2,
    const int* __restrict__ ei,
    float* __restrict__ As_t, float* __restrict__ Ad_t,
    unsigned short* __restrict__ W1bT, unsigned short* __restrict__ W2bT,
    int* __restrict__ counts, int E, int N) {
    int b = blockIdx.x;
    __shared__ unsigned short tile[32][33];
    if (b < 4) {
        int i = b * 256 + threadIdx.x;   // 0..1023
        int k = i >> 3, h = i & 7;
        float ss = 0.f, sd = 0.f;
        for (int c = 0; c < 128; c += 4) {
            float4 w = *(const float4*)(W1 + (size_t)k * 1024 + h * 128 + c);
            float4 a = *(const float4*)(a_src1 + h * 128 + c);
            float4 d = *(const float4*)(a_dst1 + h * 128 + c);
            ss += w.x * a.x + w.y * a.y + w.z * a.z + w.w * a.w;
            sd += w.x * d.x + w.y * d.y + w.z * d.z + w.w * d.w;
        }
        As_t[h * 132 + k] = ss;   // transposed, stride 132 (bank stagger)
        Ad_t[h * 132 + k] = sd;
    } else if (b < 132) {
        int bb = b - 4;
        int kt = bb & 3, hct = bb >> 2;
        int j = threadIdx.x & 31;
        int i0 = threadIdx.x >> 5;
        for (int i = i0; i < 32; i += 8)
            tile[i][j] = f2bf(W1[(size_t)(kt * 32 + i) * 1024 + hct * 32 + j]);
        __syncthreads();
        for (int i = i0; i < 32; i += 8) {
            int hc = hct * 32 + i, k = kt * 32 + j;
            int h = hc >> 7, c = hc & 127;
            W1bT[h * 16384 + c * 128 + k] = tile[j][i];
        }
    } else if (b < 196) {
        int bb = b - 132;
        int kt = bb & 31, ctile = bb >> 5;
        int j = threadIdx.x & 31;
        int i0 = threadIdx.x >> 5;
        for (int i = i0; i < 32; i += 8)
            tile[i][j] = f2bf(W2[(size_t)(kt * 32 + i) * 64 + ctile * 32 + j]);
        __syncthreads();
        for (int i = i0; i < 32; i += 8)
            W2bT[(size_t)(ctile * 32 + i) * 1024 + kt * 32 + j] = tile[j][i];
    } else {
        int i = (b - 196) * 256 + threadIdx.x;
        int M = E + N;
        if (i >= M) return;
        int dst = (i < E) ? ei[E + i] : (i - E);   // self-loop tail
        atomicAdd(&counts[dst], 1);
    }
}

// ---------------- kernel 2: alpha1 (blocks 0..nb_alpha-1) + scan (last block) -----
// 1024 threads. alpha1: 128 nodes/block, conflict-free staggered LDS.

__global__ __launch_bounds__(1024) void alpha_scan(
    const float* __restrict__ x, const float* __restrict__ As_t, const float* __restrict__ Ad_t,
    float* __restrict__ as1, float* __restrict__ ad1,
    const int* __restrict__ counts, int* __restrict__ offsets,
    int* __restrict__ cursor, int N, int nb_alpha) {
    int t = threadIdx.x;
    if ((int)blockIdx.x < nb_alpha) {
        __shared__ float sAs[1056], sAd[1056];
        for (int i = t; i < 1056; i += 1024) {
            sAs[i] = As_t[i];
            sAd[i] = Ad_t[i];
        }
        __syncthreads();
        int node = blockIdx.x * 128 + (t >> 3);
        int h = t & 7;
        if (node >= N) return;
        const float* sa = sAs + h * 132;
        const float* sd = sAd + h * 132;
        float accs = 0.f, accd = 0.f;
        for (int k = 0; k < 128; k += 4) {
            float4 xv = *(const float4*)(x + (size_t)node * 128 + k);
            float4 av = *(const float4*)(sa + k);   // banks 4h..4h+3: conflict-free
            float4 dv = *(const float4*)(sd + k);
            accs += xv.x * av.x + xv.y * av.y + xv.z * av.z + xv.w * av.w;
            accd += xv.x * dv.x + xv.y * dv.y + xv.z * dv.z + xv.w * dv.w;
        }
        as1[node * 8 + h] = accs;
        ad1[node * 8 + h] = accd;
    } else {
        __shared__ int wsum[16];
        int per = (N + 1023) / 1024;
        int base = t * per;
        int s = 0;
        for (int j = 0; j < per; j++) {
            int idx = base + j;
            if (idx < N) s += counts[idx];
        }
        int lane = t & 63, wid = t >> 6;
        int inc = s;
#pragma unroll
        for (int off = 1; off <= 32; off <<= 1) {
            int v = __shfl_up(inc, off);
            if (lane >= off) inc += v;
        }
        if (lane == 63) wsum[wid] = inc;
        __syncthreads();
        if (t < 16) {
            int v = wsum[t];
            int iv = v;
#pragma unroll
            for (int off = 1; off <= 8; off <<= 1) {
                int u = __shfl_up(iv, off);
                if (t >= off) iv += u;
            }
            wsum[t] = iv - v;   // exclusive
        }
        __syncthreads();
        int run = wsum[wid] + inc - s;
        for (int j = 0; j < per; j++) {
            int idx = base + j;
            if (idx < N) {
                offsets[idx] = run;
                cursor[idx] = run;
                run += counts[idx];
            }
        }
        if (t == 1023) offsets[N] = run;
    }
}

// ---------------- kernel 3: fill CSR + inline layer-1 softmax numerators ---------

__global__ __launch_bounds__(256) void fill_w1(
    const int* __restrict__ ei, int* __restrict__ cursor,
    const float* __restrict__ as1, const float* __restrict__ ad1,
    int* __restrict__ srcs, float* __restrict__ wbuf, int E, int N) {
    int i = blockIdx.x * blockDim.x + threadIdx.x;
    int M = E + N;
    if (i >= M) return;
    int src, dst;
    if (i < E) { src = ei[i]; dst = ei[E + i]; }
    else       { src = dst = i - E; }
    int pos = atomicAdd(&cursor[dst], 1);
    srcs[pos] = src;
    float4 a0 = *(const float4*)(as1 + (size_t)src * 8);
    float4 a1 = *(const float4*)(as1 + (size_t)src * 8 + 4);
    float4 b0 = *(const float4*)(ad1 + (size_t)dst * 8);
    float4 b1 = *(const float4*)(ad1 + (size_t)dst * 8 + 4);
    float4 w0, w1;
    w0.x = __expf(leaky(a0.x + b0.x));
    w0.y = __expf(leaky(a0.y + b0.y));
    w0.z = __expf(leaky(a0.z + b0.z));
    w0.w = __expf(leaky(a0.w + b0.w));
    w1.x = __expf(leaky(a1.x + b1.x));
    w1.y = __expf(leaky(a1.y + b1.y));
    w1.z = __expf(leaky(a1.z + b1.z));
    w1.w = __expf(leaky(a1.w + b1.w));
    *(float4*)(wbuf + (size_t)pos * 8)     = w0;
    *(float4*)(wbuf + (size_t)pos * 8 + 4) = w1;
}

// ---------------- l1_gather: wave per node, pure gather, in-register wsum --------

__global__ __launch_bounds__(256) void l1_gather(
    const float* __restrict__ x, const float* __restrict__ wbuf,
    const int* __restrict__ offsets, const int* __restrict__ srcs,
    unsigned short* __restrict__ y_b, int N) {
    int n = blockIdx.x * 4 + (threadIdx.x >> 6);
    if (n >= N) return;
    int lane = threadIdx.x & 63;
    int beg = offsets[n];
    int deg = offsets[n + 1] - beg;
    float2 acc[8];
#pragma unroll
    for (int h = 0; h < 8; h++) acc[h] = make_float2(0.f, 0.f);
    float4 ws0 = make_float4(0.f, 0.f, 0.f, 0.f);
    float4 ws1 = make_float4(0.f, 0.f, 0.f, 0.f);
    const float* xb = x + lane * 2;
#define L1G_BODY(I)                                                              \
    {                                                                            \
        int s_ = srcs[beg + (I)];                                                \
        float4 w0_ = *(const float4*)(wbuf + (size_t)(beg + (I)) * 8);           \
        float4 w1_ = *(const float4*)(wbuf + (size_t)(beg + (I)) * 8 + 4);       \
        float2 xv_ = *(const float2*)(xb + (size_t)s_ * 128);                    \
        ws0.x += w0_.x; ws0.y += w0_.y; ws0.z += w0_.z; ws0.w += w0_.w;          \
        ws1.x += w1_.x; ws1.y += w1_.y; ws1.z += w1_.z; ws1.w += w1_.w;          \
        acc[0].x = fmaf(w0_.x, xv_.x, acc[0].x); acc[0].y = fmaf(w0_.x, xv_.y, acc[0].y); \
        acc[1].x = fmaf(w0_.y, xv_.x, acc[1].x); acc[1].y = fmaf(w0_.y, xv_.y, acc[1].y); \
        acc[2].x = fmaf(w0_.z, xv_.x, acc[2].x); acc[2].y = fmaf(w0_.z, xv_.y, acc[2].y); \
        acc[3].x = fmaf(w0_.w, xv_.x, acc[3].x); acc[3].y = fmaf(w0_.w, xv_.y, acc[3].y); \
        acc[4].x = fmaf(w1_.x, xv_.x, acc[4].x); acc[4].y = fmaf(w1_.x, xv_.y, acc[4].y); \
        acc[5].x = fmaf(w1_.y, xv_.x, acc[5].x); acc[5].y = fmaf(w1_.y, xv_.y, acc[5].y); \
        acc[6].x = fmaf(w1_.z, xv_.x, acc[6].x); acc[6].y = fmaf(w1_.z, xv_.y, acc[6].y); \
        acc[7].x = fmaf(w1_.w, xv_.x, acc[7].x); acc[7].y = fmaf(w1_.w, xv_.y, acc[7].y); \
    }
    int i = 0;
    for (; i + 4 <= deg; i += 4) {       // 4 edges in flight
        L1G_BODY(i) L1G_BODY(i + 1) L1G_BODY(i + 2) L1G_BODY(i + 3)
    }
    for (; i < deg; i++) { L1G_BODY(i) }
#undef L1G_BODY
    float inv[8] = {1.f / (ws0.x + 1e-16f), 1.f / (ws0.y + 1e-16f),
                    1.f / (ws0.z + 1e-16f), 1.f / (ws0.w + 1e-16f),
                    1.f / (ws1.x + 1e-16f), 1.f / (ws1.y + 1e-16f),
                    1.f / (ws1.z + 1e-16f), 1.f / (ws1.w + 1e-16f)};
    unsigned short* dst = y_b + (size_t)n * 1024 + lane * 2;
#pragma unroll
    for (int h = 0; h < 8; h++) {
        unsigned lo = f2bf(acc[h].x * inv[h]);
        unsigned hi = f2bf(acc[h].y * inv[h]);
        *(unsigned*)(dst + h * 128) = lo | (hi << 16);   // coalesced per head
    }
}

// ---------------- l1_gemm (MFMA): hbuf_b = ELU(per-head y @ W1h + b1), bf16 out ----

__global__ __launch_bounds__(256) void l1_gemm(
    const unsigned short* __restrict__ y_b, const unsigned short* __restrict__ W1bT,
    const float* __restrict__ b1, unsigned short* __restrict__ hbuf_b, int N) {
    int h  = blockIdx.x & 7;
    int nb = (blockIdx.x >> 3) * 64;
    int w  = threadIdx.x >> 6;
    int lane = threadIdx.x & 63;
    int n16 = lane & 15, quad = lane >> 4;
    int node_a = nb + w * 16 + n16;
    const unsigned short* yrow =
        y_b + (size_t)(node_a < N ? node_a : 0) * 1024 + h * 128 + quad * 8;
    const unsigned short* Wh = W1bT + h * 16384 + quad * 8;
    f32x4 acc[8];
#pragma unroll
    for (int ct = 0; ct < 8; ct++) acc[ct] = (f32x4){0.f, 0.f, 0.f, 0.f};
#pragma unroll
    for (int ks = 0; ks < 4; ks++) {
        bf16x8 a = *(const bf16x8*)(yrow + ks * 32);
#pragma unroll
        for (int ct = 0; ct < 8; ct++) {
            bf16x8 b = *(const bf16x8*)(Wh + (ct * 16 + n16) * 128 + ks * 32);
            acc[ct] = __builtin_amdgcn_mfma_f32_16x16x32_bf16(a, b, acc[ct], 0, 0, 0);
        }
    }
#pragma unroll
    for (int ct = 0; ct < 8; ct++) {
        int c = h * 128 + ct * 16 + n16;
        float bias = b1[c];
#pragma unroll
        for (int r = 0; r < 4; r++) {
            int node = nb + w * 16 + quad * 4 + r;
            if (node < N) {
                float v = acc[ct][r] + bias;
                v = v > 0.f ? v : expm1f(v);
                hbuf_b[(size_t)node * 1024 + c] = f2bf(v);
            }
        }
    }
}

// ---------------- l2_transform (MFMA, K-split x2): h2 = hbuf @ W2, as2/ad2 --------
// Block = (16-node tile, ct-pair). Wave: ct = cp*2+(w>>1), K-half kh = w&1.
// K-halves LDS-reduced; alpha2 logits accumulated by atomicAdd (as2/ad2 pre-zeroed).

__global__ __launch_bounds__(256) void l2_transform(
    const unsigned short* __restrict__ hbuf_b, const unsigned short* __restrict__ W2bT,
    const float* __restrict__ a_src2, const float* __restrict__ a_dst2,
    float* __restrict__ h2, float* __restrict__ as2, float* __restrict__ ad2, int N) {
    int nt = blockIdx.x >> 1;
    int cp = blockIdx.x & 1;
    int nb = nt * 16;
    int w = threadIdx.x >> 6;
    int lane = threadIdx.x & 63;
    int n16 = lane & 15, quad = lane >> 4;
    int ct = cp * 2 + (w >> 1);
    int kh = w & 1;
    int node_a = nb + n16;
    const unsigned short* arow =
        hbuf_b + (size_t)(node_a < N ? node_a : N - 1) * 1024 + kh * 512 + quad * 8;
    const unsigned short* brow =
        W2bT + (size_t)(ct * 16 + n16) * 1024 + kh * 512 + quad * 8;
    f32x4 acc = (f32x4){0.f, 0.f, 0.f, 0.f};
#pragma unroll
    for (int ks = 0; ks < 16; ks++) {
        bf16x8 a = *(const bf16x8*)(arow + ks * 32);
        bf16x8 b = *(const bf16x8*)(brow + ks * 32);
        acc = __builtin_amdgcn_mfma_f32_16x16x32_bf16(a, b, acc, 0, 0, 0);
    }
    __shared__ float red[2][64][4];
    if (kh == 1) {
#pragma unroll
        for (int r = 0; r < 4; r++) red[w >> 1][lane][r] = acc[r];
    }
    __syncthreads();
    if (kh == 1) return;
#pragma unroll
    for (int r = 0; r < 4; r++) acc[r] += red[w >> 1][lane][r];
    int c = ct * 16 + n16;
    float asc = a_src2[c], adc = a_dst2[c];
    float pav[4], pdv[4];
#pragma unroll
    for (int r = 0; r < 4; r++) {
        int node = nb + quad * 4 + r;
        if (node < N) h2[(size_t)node * 64 + c] = acc[r];
        pav[r] = acc[r] * asc;
        pdv[r] = acc[r] * adc;
#pragma unroll
        for (int mm = 1; mm <= 8; mm <<= 1) {   // reduce over n16 within quad group
            pav[r] += __shfl_xor(pav[r], mm);
            pdv[r] += __shfl_xor(pdv[r], mm);
        }
    }
    if (n16 == 0) {
#pragma unroll
        for (int r = 0; r < 4; r++) {
            int node = nb + quad * 4 + r;
            if (node < N) {
                atomicAdd(&as2[node], pav[r]);   // 4 adds/node total (2 blocks x 2 ct)
                atomicAdd(&ad2[node], pdv[r]);
            }
        }
    }
}

// ---------------- l2_gather: wave per node, inline weights, in-register wsum -----

__global__ __launch_bounds__(256) void l2_gather(
    const float* __restrict__ h2, const float* __restrict__ as2,
    const float* __restrict__ ad2, const float* __restrict__ b2,
    const int* __restrict__ offsets, const int* __restrict__ srcs,
    float* __restrict__ out, int N) {
    int n = blockIdx.x * 4 + (threadIdx.x >> 6);
    if (n >= N) return;
    int lane = threadIdx.x & 63;
    int beg = offsets[n];
    int deg = offsets[n + 1] - beg;
    float adn = ad2[n];
    float acc = 0.f, wsum = 0.f;
    int i = 0;
    for (; i + 4 <= deg; i += 4) {
        int s0 = srcs[beg + i],     s1 = srcs[beg + i + 1];
        int s2 = srcs[beg + i + 2], s3 = srcs[beg + i + 3];
        float w0 = __expf(leaky(as2[s0] + adn));   // same addr all lanes -> broadcast
        float w1 = __expf(leaky(as2[s1] + adn));
        float w2 = __expf(leaky(as2[s2] + adn));
        float w3 = __expf(leaky(as2[s3] + adn));
        float v0 = h2[(size_t)s0 * 64 + lane];
        float v1 = h2[(size_t)s1 * 64 + lane];
        float v2 = h2[(size_t)s2 * 64 + lane];
        float v3 = h2[(size_t)s3 * 64 + lane];
        wsum += w0 + w1 + w2 + w3;
        acc = fmaf(w0, v0, acc);
        acc = fmaf(w1, v1, acc);
        acc = fmaf(w2, v2, acc);
        acc = fmaf(w3, v3, acc);
    }
    for (; i < deg; i++) {
        int s = srcs[beg + i];
        float w = __expf(leaky(as2[s] + adn));
        wsum += w;
        acc = fmaf(w, h2[(size_t)s * 64 + lane], acc);
    }
    out[(size_t)n * 64 + lane] = acc / (wsum + 1e-16f) + b2[lane];
}

// ---------------- launch ----------------

static inline size_t align_up(size_t v, size_t a) { return (v + a - 1) / a * a; }

extern "C" void kernel_launch(void* const* d_in, const int* in_sizes, int n_in,
                              void* d_out, int out_size, void* d_ws, size_t ws_size,
                              hipStream_t stream) {
    const float* x      = (const float*)d_in[0];
    const int*   ei     = (const int*)d_in[1];
    const float* W1     = (const float*)d_in[2];
    const float* a_src1 = (const float*)d_in[3];
    const float* a_dst1 = (const float*)d_in[4];
    const float* b1     = (const float*)d_in[5];
    const float* W2     = (const float*)d_in[6];
    const float* a_src2 = (const float*)d_in[7];
    const float* a_dst2 = (const float*)d_in[8];
    const float* b2     = (const float*)d_in[9];
    float* out = (float*)d_out;

    int N = in_sizes[0] / 128;
    int E = in_sizes[1] / 2;
    int M = E + N;

    char* p = (char*)d_ws;
    size_t off = 0;
    auto carve = [&](size_t bytes) {
        void* r = p + off;
        off = align_up(off + bytes, 256);
        return r;
    };
    // zero-init region: counts + as2 + ad2 (carved adjacently)
    int*            counts  = (int*)carve((size_t)N * 4);
    float*          as2     = (float*)carve((size_t)N * 4);
    float*          ad2     = (float*)carve((size_t)N * 4);
    size_t zero_span = off;
    int*            offsets = (int*)carve((size_t)(N + 1) * 4);
    int*            cursor  = (int*)carve((size_t)N * 4);
    int*            srcs    = (int*)carve((size_t)M * 4);
    float*          As_t    = (float*)carve(1056 * 4);
    float*          Ad_t    = (float*)carve(1056 * 4);
    float*          as1     = (float*)carve((size_t)N * 8 * 4);
    float*          ad1     = (float*)carve((size_t)N * 8 * 4);
    float*          h2      = (float*)carve((size_t)N * 64 * 4);
    float*          wbuf    = (float*)carve((size_t)M * 8 * 4);
    unsigned short* W1bT    = (unsigned short*)carve((size_t)8 * 128 * 128 * 2);
    unsigned short* W2bT    = (unsigned short*)carve((size_t)64 * 1024 * 2);
    unsigned short* y_b     = (unsigned short*)carve((size_t)N * 1024 * 2);
    unsigned short* hbuf_b  = (unsigned short*)carve((size_t)N * 1024 * 2);
    (void)ws_size; // ~60 MB

    int nb_count = (M + 255) / 256;
    int nb_alpha = (N + 127) / 128;

    hipMemsetAsync(counts, 0, zero_span, stream);
    prep_count<<<196 + nb_count, 256, 0, stream>>>(W1, a_src1, a_dst1, W2, ei,
                                                   As_t, Ad_t, W1bT, W2bT, counts, E, N);
    alpha_scan<<<nb_alpha + 1, 1024, 0, stream>>>(x, As_t, Ad_t, as1, ad1,
                                                  counts, offsets, cursor, N, nb_alpha);
    fill_w1<<<nb_count, 256, 0, stream>>>(ei, cursor, as1, ad1, srcs, wbuf, E, N);
    l1_gather<<<(N + 3) / 4, 256, 0, stream>>>(x, wbuf, offsets, srcs, y_b, N);
    l1_gemm<<<((N + 63) / 64) * 8, 256, 0, stream>>>(y_b, W1bT, b1, hbuf_b, N);
    l2_transform<<<((N + 15) / 16) * 2, 256, 0, stream>>>(hbuf_b, W2bT, a_src2, a_dst2,
                                                          h2, as2, ad2, N);
    l2_gather<<<(N + 3) / 4, 256, 0, stream>>>(h2, as2, ad2, b2, offsets, srcs, out, N);
}

// Round 15
// 192.829 us; speedup vs baseline: 1.7219x; 1.0852x over previous
//
#include <hip/hip_runtime.h>
#include <math.h>

// GAT 2-layer: N=10000, E=160000 (+N self loops), IN=128, H1=8, C1=128, OUT=64.
// R15: l1_gemm + l2_transform fused (l12_gemm): hbuf lives in LDS per 16-node
//      tile -- removes 40 MB round-trip + 1 dispatch. 7 dispatches total.
// GEMMs bf16 MFMA (fp32 accumulate); softmax path fp32.

#define NEG_SLOPE 0.2f

typedef short bf16x8 __attribute__((ext_vector_type(8)));
typedef float f32x4 __attribute__((ext_vector_type(4)));

__device__ __forceinline__ float leaky(float v) { return v >= 0.0f ? v : NEG_SLOPE * v; }

__device__ __forceinline__ unsigned short f2bf(float f) {
    unsigned u = __float_as_uint(f);
    u += 0x7FFFu + ((u >> 16) & 1u);   // round-to-nearest-even
    return (unsigned short)(u >> 16);
}

// ---------------- kernel 1: prep (As_t/Ad_t, W1bT, W2bT) + edge count ----------------

__global__ __launch_bounds__(256) void prep_count(
    const float* __restrict__ W1, const float* __restrict__ a_src1,
    const float* __restrict__ a_dst1, const float* __restrict__ W2,
    const int* __restrict__ ei,
    float* __restrict__ As_t, float* __restrict__ Ad_t,
    unsigned short* __restrict__ W1bT, unsigned short* __restrict__ W2bT,
    int* __restrict__ counts, int E, int N) {
    int b = blockIdx.x;
    __shared__ unsigned short tile[32][33];
    if (b < 4) {
        int i = b * 256 + threadIdx.x;   // 0..1023
        int k = i >> 3, h = i & 7;
        float ss = 0.f, sd = 0.f;
        for (int c = 0; c < 128; c += 4) {
            float4 w = *(const float4*)(W1 + (size_t)k * 1024 + h * 128 + c);
            float4 a = *(const float4*)(a_src1 + h * 128 + c);
            float4 d = *(const float4*)(a_dst1 + h * 128 + c);
            ss += w.x * a.x + w.y * a.y + w.z * a.z + w.w * a.w;
            sd += w.x * d.x + w.y * d.y + w.z * d.z + w.w * d.w;
        }
        As_t[h * 132 + k] = ss;   // transposed, stride 132 (bank stagger)
        Ad_t[h * 132 + k] = sd;
    } else if (b < 132) {
        int bb = b - 4;
        int kt = bb & 3, hct = bb >> 2;
        int j = threadIdx.x & 31;
        int i0 = threadIdx.x >> 5;
        for (int i = i0; i < 32; i += 8)
            tile[i][j] = f2bf(W1[(size_t)(kt * 32 + i) * 1024 + hct * 32 + j]);
        __syncthreads();
        for (int i = i0; i < 32; i += 8) {
            int hc = hct * 32 + i, k = kt * 32 + j;
            int h = hc >> 7, c = hc & 127;
            W1bT[h * 16384 + c * 128 + k] = tile[j][i];
        }
    } else if (b < 196) {
        int bb = b - 132;
        int kt = bb & 31, ctile = bb >> 5;
        int j = threadIdx.x & 31;
        int i0 = threadIdx.x >> 5;
        for (int i = i0; i < 32; i += 8)
            tile[i][j] = f2bf(W2[(size_t)(kt * 32 + i) * 64 + ctile * 32 + j]);
        __syncthreads();
        for (int i = i0; i < 32; i += 8)
            W2bT[(size_t)(ctile * 32 + i) * 1024 + kt * 32 + j] = tile[j][i];
    } else {
        int i = (b - 196) * 256 + threadIdx.x;
        int M = E + N;
        if (i >= M) return;
        int dst = (i < E) ? ei[E + i] : (i - E);   // self-loop tail
        atomicAdd(&counts[dst], 1);
    }
}

// ---------------- kernel 2: alpha1 + scan (last block) ----------------

__global__ __launch_bounds__(1024) void alpha_scan(
    const float* __restrict__ x, const float* __restrict__ As_t, const float* __restrict__ Ad_t,
    float* __restrict__ as1, float* __restrict__ ad1,
    const int* __restrict__ counts, int* __restrict__ offsets,
    int* __restrict__ cursor, int N, int nb_alpha) {
    int t = threadIdx.x;
    if ((int)blockIdx.x < nb_alpha) {
        __shared__ float sAs[1056], sAd[1056];
        for (int i = t; i < 1056; i += 1024) {
            sAs[i] = As_t[i];
            sAd[i] = Ad_t[i];
        }
        __syncthreads();
        int node = blockIdx.x * 128 + (t >> 3);
        int h = t & 7;
        if (node >= N) return;
        const float* sa = sAs + h * 132;
        const float* sd = sAd + h * 132;
        float accs = 0.f, accd = 0.f;
        for (int k = 0; k < 128; k += 4) {
            float4 xv = *(const float4*)(x + (size_t)node * 128 + k);
            float4 av = *(const float4*)(sa + k);
            float4 dv = *(const float4*)(sd + k);
            accs += xv.x * av.x + xv.y * av.y + xv.z * av.z + xv.w * av.w;
            accd += xv.x * dv.x + xv.y * dv.y + xv.z * dv.z + xv.w * dv.w;
        }
        as1[node * 8 + h] = accs;
        ad1[node * 8 + h] = accd;
    } else {
        __shared__ int wsum[16];
        int per = (N + 1023) / 1024;
        int base = t * per;
        int s = 0;
        for (int j = 0; j < per; j++) {
            int idx = base + j;
            if (idx < N) s += counts[idx];
        }
        int lane = t & 63, wid = t >> 6;
        int inc = s;
#pragma unroll
        for (int off = 1; off <= 32; off <<= 1) {
            int v = __shfl_up(inc, off);
            if (lane >= off) inc += v;
        }
        if (lane == 63) wsum[wid] = inc;
        __syncthreads();
        if (t < 16) {
            int v = wsum[t];
            int iv = v;
#pragma unroll
            for (int off = 1; off <= 8; off <<= 1) {
                int u = __shfl_up(iv, off);
                if (t >= off) iv += u;
            }
            wsum[t] = iv - v;   // exclusive
        }
        __syncthreads();
        int run = wsum[wid] + inc - s;
        for (int j = 0; j < per; j++) {
            int idx = base + j;
            if (idx < N) {
                offsets[idx] = run;
                cursor[idx] = run;
                run += counts[idx];
            }
        }
        if (t == 1023) offsets[N] = run;
    }
}

// ---------------- kernel 3: fill CSR + inline layer-1 softmax numerators ---------

__global__ __launch_bounds__(256) void fill_w1(
    const int* __restrict__ ei, int* __restrict__ cursor,
    const float* __restrict__ as1, const float* __restrict__ ad1,
    int* __restrict__ srcs, float* __restrict__ wbuf, int E, int N) {
    int i = blockIdx.x * blockDim.x + threadIdx.x;
    int M = E + N;
    if (i >= M) return;
    int src, dst;
    if (i < E) { src = ei[i]; dst = ei[E + i]; }
    else       { src = dst = i - E; }
    int pos = atomicAdd(&cursor[dst], 1);
    srcs[pos] = src;
    float4 a0 = *(const float4*)(as1 + (size_t)src * 8);
    float4 a1 = *(const float4*)(as1 + (size_t)src * 8 + 4);
    float4 b0 = *(const float4*)(ad1 + (size_t)dst * 8);
    float4 b1 = *(const float4*)(ad1 + (size_t)dst * 8 + 4);
    float4 w0, w1;
    w0.x = __expf(leaky(a0.x + b0.x));
    w0.y = __expf(leaky(a0.y + b0.y));
    w0.z = __expf(leaky(a0.z + b0.z));
    w0.w = __expf(leaky(a0.w + b0.w));
    w1.x = __expf(leaky(a1.x + b1.x));
    w1.y = __expf(leaky(a1.y + b1.y));
    w1.z = __expf(leaky(a1.z + b1.z));
    w1.w = __expf(leaky(a1.w + b1.w));
    *(float4*)(wbuf + (size_t)pos * 8)     = w0;
    *(float4*)(wbuf + (size_t)pos * 8 + 4) = w1;
}

// ---------------- l1_gather: wave per node, pure gather, in-register wsum --------

__global__ __launch_bounds__(256) void l1_gather(
    const float* __restrict__ x, const float* __restrict__ wbuf,
    const int* __restrict__ offsets, const int* __restrict__ srcs,
    unsigned short* __restrict__ y_b, int N) {
    int n = blockIdx.x * 4 + (threadIdx.x >> 6);
    if (n >= N) return;
    int lane = threadIdx.x & 63;
    int beg = offsets[n];
    int deg = offsets[n + 1] - beg;
    float2 acc[8];
#pragma unroll
    for (int h = 0; h < 8; h++) acc[h] = make_float2(0.f, 0.f);
    float4 ws0 = make_float4(0.f, 0.f, 0.f, 0.f);
    float4 ws1 = make_float4(0.f, 0.f, 0.f, 0.f);
    const float* xb = x + lane * 2;
#define L1G_BODY(I)                                                              \
    {                                                                            \
        int s_ = srcs[beg + (I)];                                                \
        float4 w0_ = *(const float4*)(wbuf + (size_t)(beg + (I)) * 8);           \
        float4 w1_ = *(const float4*)(wbuf + (size_t)(beg + (I)) * 8 + 4);       \
        float2 xv_ = *(const float2*)(xb + (size_t)s_ * 128);                    \
        ws0.x += w0_.x; ws0.y += w0_.y; ws0.z += w0_.z; ws0.w += w0_.w;          \
        ws1.x += w1_.x; ws1.y += w1_.y; ws1.z += w1_.z; ws1.w += w1_.w;          \
        acc[0].x = fmaf(w0_.x, xv_.x, acc[0].x); acc[0].y = fmaf(w0_.x, xv_.y, acc[0].y); \
        acc[1].x = fmaf(w0_.y, xv_.x, acc[1].x); acc[1].y = fmaf(w0_.y, xv_.y, acc[1].y); \
        acc[2].x = fmaf(w0_.z, xv_.x, acc[2].x); acc[2].y = fmaf(w0_.z, xv_.y, acc[2].y); \
        acc[3].x = fmaf(w0_.w, xv_.x, acc[3].x); acc[3].y = fmaf(w0_.w, xv_.y, acc[3].y); \
        acc[4].x = fmaf(w1_.x, xv_.x, acc[4].x); acc[4].y = fmaf(w1_.x, xv_.y, acc[4].y); \
        acc[5].x = fmaf(w1_.y, xv_.x, acc[5].x); acc[5].y = fmaf(w1_.y, xv_.y, acc[5].y); \
        acc[6].x = fmaf(w1_.z, xv_.x, acc[6].x); acc[6].y = fmaf(w1_.z, xv_.y, acc[6].y); \
        acc[7].x = fmaf(w1_.w, xv_.x, acc[7].x); acc[7].y = fmaf(w1_.w, xv_.y, acc[7].y); \
    }
    int i = 0;
    for (; i + 4 <= deg; i += 4) {       // 4 edges in flight
        L1G_BODY(i) L1G_BODY(i + 1) L1G_BODY(i + 2) L1G_BODY(i + 3)
    }
    for (; i < deg; i++) { L1G_BODY(i) }
#undef L1G_BODY
    float inv[8] = {1.f / (ws0.x + 1e-16f), 1.f / (ws0.y + 1e-16f),
                    1.f / (ws0.z + 1e-16f), 1.f / (ws0.w + 1e-16f),
                    1.f / (ws1.x + 1e-16f), 1.f / (ws1.y + 1e-16f),
                    1.f / (ws1.z + 1e-16f), 1.f / (ws1.w + 1e-16f)};
    unsigned short* dst = y_b + (size_t)n * 1024 + lane * 2;
#pragma unroll
    for (int h = 0; h < 8; h++) {
        unsigned lo = f2bf(acc[h].x * inv[h]);
        unsigned hi = f2bf(acc[h].y * inv[h]);
        *(unsigned*)(dst + h * 128) = lo | (hi << 16);   // coalesced per head
    }
}

// ---------------- l12_gemm (MFMA, fused): LDS hbuf -> h2, as2/ad2 ----------------
// Block = 16 nodes (N=10000 -> exactly 625 tiles).
// Phase A: wave w computes col-tiles ct = w*16..w*16+15 of ELU(y@W1+b1) -> LDS
//          (row stride 1032 shorts: <=2-way banks).
// Phase B: wave w computes h2 cols w*16..+15 (K=1024 from LDS) + alpha2 logits.

__global__ __launch_bounds__(256) void l12_gemm(
    const unsigned short* __restrict__ y_b, const unsigned short* __restrict__ W1bT,
    const float* __restrict__ b1, const unsigned short* __restrict__ W2bT,
    const float* __restrict__ a_src2, const float* __restrict__ a_dst2,
    float* __restrict__ h2, float* __restrict__ as2, float* __restrict__ ad2, int N) {
    int nb = blockIdx.x * 16;
    int w = threadIdx.x >> 6;
    int lane = threadIdx.x & 63;
    int n16 = lane & 15, quad = lane >> 4;
    __shared__ unsigned short hb[16 * 1032];   // 33 KB
    __shared__ float sA[4][16], sD[4][16];
    // ---- phase A ----
    int node_a = nb + n16;
    const unsigned short* yrow = y_b + (size_t)(node_a < N ? node_a : 0) * 1024;
#pragma unroll
    for (int cti = 0; cti < 16; cti++) {
        int ct = w * 16 + cti;          // 0..63
        int h = ct >> 3;
        int cc = (ct & 7) * 16;
        const unsigned short* Wh = W1bT + h * 16384 + (size_t)(cc + n16) * 128 + quad * 8;
        const unsigned short* ya = yrow + h * 128 + quad * 8;
        f32x4 acc = (f32x4){0.f, 0.f, 0.f, 0.f};
#pragma unroll
        for (int ks = 0; ks < 4; ks++) {
            bf16x8 a = *(const bf16x8*)(ya + ks * 32);
            bf16x8 b = *(const bf16x8*)(Wh + ks * 32);
            acc = __builtin_amdgcn_mfma_f32_16x16x32_bf16(a, b, acc, 0, 0, 0);
        }
        int c = h * 128 + cc + n16;     // global channel
        float bias = b1[c];
#pragma unroll
        for (int r = 0; r < 4; r++) {
            float v = acc[r] + bias;
            v = v > 0.f ? v : expm1f(v);
            hb[(quad * 4 + r) * 1032 + c] = f2bf(v);
        }
    }
    __syncthreads();
    // ---- phase B ----
    const unsigned short* arow = hb + n16 * 1032 + quad * 8;
    const unsigned short* brow = W2bT + (size_t)(w * 16 + n16) * 1024 + quad * 8;
    f32x4 acc = (f32x4){0.f, 0.f, 0.f, 0.f};
#pragma unroll 8
    for (int ks = 0; ks < 32; ks++) {
        bf16x8 a = *(const bf16x8*)(arow + ks * 32);
        bf16x8 b = *(const bf16x8*)(brow + ks * 32);
        acc = __builtin_amdgcn_mfma_f32_16x16x32_bf16(a, b, acc, 0, 0, 0);
    }
    int c2 = w * 16 + n16;
    float asc = a_src2[c2], adc = a_dst2[c2];
    float pav[4], pdv[4];
#pragma unroll
    for (int r = 0; r < 4; r++) {
        int node = nb + quad * 4 + r;
        if (node < N) h2[(size_t)node * 64 + c2] = acc[r];
        pav[r] = acc[r] * asc;
        pdv[r] = acc[r] * adc;
#pragma unroll
        for (int mm = 1; mm <= 8; mm <<= 1) {   // reduce over the 16 n16 lanes
            pav[r] += __shfl_xor(pav[r], mm);
            pdv[r] += __shfl_xor(pdv[r], mm);
        }
    }
    if (n16 == 0) {
#pragma unroll
        for (int r = 0; r < 4; r++) {
            sA[w][quad * 4 + r] = pav[r];
            sD[w][quad * 4 + r] = pdv[r];
        }
    }
    __syncthreads();
    if (threadIdx.x < 16) {
        int node = nb + threadIdx.x;
        if (node < N) {
            as2[node] = sA[0][threadIdx.x] + sA[1][threadIdx.x] + sA[2][threadIdx.x] + sA[3][threadIdx.x];
            ad2[node] = sD[0][threadIdx.x] + sD[1][threadIdx.x] + sD[2][threadIdx.x] + sD[3][threadIdx.x];
        }
    }
}

// ---------------- l2_gather: wave per node, inline weights, in-register wsum -----

__global__ __launch_bounds__(256) void l2_gather(
    const float* __restrict__ h2, const float* __restrict__ as2,
    const float* __restrict__ ad2, const float* __restrict__ b2,
    const int* __restrict__ offsets, const int* __restrict__ srcs,
    float* __restrict__ out, int N) {
    int n = blockIdx.x * 4 + (threadIdx.x >> 6);
    if (n >= N) return;
    int lane = threadIdx.x & 63;
    int beg = offsets[n];
    int deg = offsets[n + 1] - beg;
    float adn = ad2[n];
    float acc = 0.f, wsum = 0.f;
    int i = 0;
    for (; i + 4 <= deg; i += 4) {
        int s0 = srcs[beg + i],     s1 = srcs[beg + i + 1];
        int s2 = srcs[beg + i + 2], s3 = srcs[beg + i + 3];
        float w0 = __expf(leaky(as2[s0] + adn));   // same addr all lanes -> broadcast
        float w1 = __expf(leaky(as2[s1] + adn));
        float w2 = __expf(leaky(as2[s2] + adn));
        float w3 = __expf(leaky(as2[s3] + adn));
        float v0 = h2[(size_t)s0 * 64 + lane];
        float v1 = h2[(size_t)s1 * 64 + lane];
        float v2 = h2[(size_t)s2 * 64 + lane];
        float v3 = h2[(size_t)s3 * 64 + lane];
        wsum += w0 + w1 + w2 + w3;
        acc = fmaf(w0, v0, acc);
        acc = fmaf(w1, v1, acc);
        acc = fmaf(w2, v2, acc);
        acc = fmaf(w3, v3, acc);
    }
    for (; i < deg; i++) {
        int s = srcs[beg + i];
        float w = __expf(leaky(as2[s] + adn));
        wsum += w;
        acc = fmaf(w, h2[(size_t)s * 64 + lane], acc);
    }
    out[(size_t)n * 64 + lane] = acc / (wsum + 1e-16f) + b2[lane];
}

// ---------------- launch ----------------

static inline size_t align_up(size_t v, size_t a) { return (v + a - 1) / a * a; }

extern "C" void kernel_launch(void* const* d_in, const int* in_sizes, int n_in,
                              void* d_out, int out_size, void* d_ws, size_t ws_size,
                              hipStream_t stream) {
    const float* x      = (const float*)d_in[0];
    const int*   ei     = (const int*)d_in[1];
    const float* W1     = (const float*)d_in[2];
    const float* a_src1 = (const float*)d_in[3];
    const float* a_dst1 = (const float*)d_in[4];
    const float* b1     = (const float*)d_in[5];
    const float* W2     = (const float*)d_in[6];
    const float* a_src2 = (const float*)d_in[7];
    const float* a_dst2 = (const float*)d_in[8];
    const float* b2     = (const float*)d_in[9];
    float* out = (float*)d_out;

    int N = in_sizes[0] / 128;
    int E = in_sizes[1] / 2;
    int M = E + N;

    char* p = (char*)d_ws;
    size_t off = 0;
    auto carve = [&](size_t bytes) {
        void* r = p + off;
        off = align_up(off + bytes, 256);
        return r;
    };
    int*            counts  = (int*)carve((size_t)N * 4);
    int*            offsets = (int*)carve((size_t)(N + 1) * 4);
    int*            cursor  = (int*)carve((size_t)N * 4);
    int*            srcs    = (int*)carve((size_t)M * 4);
    float*          As_t    = (float*)carve(1056 * 4);
    float*          Ad_t    = (float*)carve(1056 * 4);
    float*          as1     = (float*)carve((size_t)N * 8 * 4);
    float*          ad1     = (float*)carve((size_t)N * 8 * 4);
    float*          as2     = (float*)carve((size_t)N * 4);
    float*          ad2     = (float*)carve((size_t)N * 4);
    float*          h2      = (float*)carve((size_t)N * 64 * 4);
    float*          wbuf    = (float*)carve((size_t)M * 8 * 4);
    unsigned short* W1bT    = (unsigned short*)carve((size_t)8 * 128 * 128 * 2);
    unsigned short* W2bT    = (unsigned short*)carve((size_t)64 * 1024 * 2);
    unsigned short* y_b     = (unsigned short*)carve((size_t)N * 1024 * 2);
    (void)ws_size; // ~40 MB

    int nb_count = (M + 255) / 256;
    int nb_alpha = (N + 127) / 128;

    hipMemsetAsync(counts, 0, (size_t)N * 4, stream);
    prep_count<<<196 + nb_count, 256, 0, stream>>>(W1, a_src1, a_dst1, W2, ei,
                                                   As_t, Ad_t, W1bT, W2bT, counts, E, N);
    alpha_scan<<<nb_alpha + 1, 1024, 0, stream>>>(x, As_t, Ad_t, as1, ad1,
                                                  counts, offsets, cursor, N, nb_alpha);
    fill_w1<<<nb_count, 256, 0, stream>>>(ei, cursor, as1, ad1, srcs, wbuf, E, N);
    l1_gather<<<(N + 3) / 4, 256, 0, stream>>>(x, wbuf, offsets, srcs, y_b, N);
    l12_gemm<<<(N + 15) / 16, 256, 0, stream>>>(y_b, W1bT, b1, W2bT, a_src2, a_dst2,
                                                h2, as2, ad2, N);
    l2_gather<<<(N + 3) / 4, 256, 0, stream>>>(h2, as2, ad2, b2, offsets, srcs, out, N);
}